// Round 10
// baseline (227.236 us; speedup 1.0000x reference)
//
#include <hip/hip_runtime.h>
#include <hip/hip_bf16.h>
#include <stdint.h>

#define GPART 512      // partition grid blocks
#define BSHIFT 9
#define BSIZE 512      // nodes per bucket
#define MAXNB 512      // LDS histogram capacity (N up to 262144)

typedef short short8 __attribute__((ext_vector_type(8)));
typedef float f32x4 __attribute__((ext_vector_type(4)));
union U4S8 { uint4 u; short8 s; };

// ---------- bf16 helpers (raw-bits; RNE pack) ----------
static __device__ __forceinline__ float bflo(uint32_t h){ return __uint_as_float(h << 16); }
static __device__ __forceinline__ float bfhi(uint32_t h){ return __uint_as_float(h & 0xFFFF0000u); }
static __device__ __forceinline__ uint32_t f2bf_bits(float f){
  uint32_t u = __float_as_uint(f);
  return (u + 0x7FFFu + ((u >> 16) & 1u)) >> 16;
}
static __device__ __forceinline__ uint32_t pack2bf(float lo, float hi){
  return f2bf_bits(lo) | (f2bf_bits(hi) << 16);
}

// ---------- partition pass 1: per-(block,bucket) histogram ----------
__global__ __launch_bounds__(256) void k_hist(const int* __restrict__ dst, int E, int NB,
    int* __restrict__ gHist){
  __shared__ int lh[MAXNB];
  int blk = blockIdx.x;
  for (int i = threadIdx.x; i < NB; i += 256) lh[i] = 0;
  __syncthreads();
  int chunk = (E + GPART - 1) / GPART;
  int e0 = blk * chunk, e1 = min(E, e0 + chunk);
  for (int e = e0 + threadIdx.x; e < e1; e += 256)
    atomicAdd(&lh[dst[e] >> BSHIFT], 1);
  __syncthreads();
  for (int i = threadIdx.x; i < NB; i += 256) gHist[i * GPART + blk] = lh[i];
}

// ---------- partition pass 2a: scan block counts within each bucket ----------
__global__ __launch_bounds__(64) void k_scanA(int* __restrict__ gHist,
    int* __restrict__ bucketTotal){
  int b = blockIdx.x;
  int lane = threadIdx.x;
  int carry = 0;
  #pragma unroll
  for (int r = 0; r < GPART/64; ++r){
    int v = gHist[b*GPART + r*64 + lane];
    int pref = v;
    #pragma unroll
    for (int off = 1; off < 64; off <<= 1){ int t = __shfl_up(pref, off); if (lane >= off) pref += t; }
    int tot = __shfl(pref, 63);
    gHist[b*GPART + r*64 + lane] = carry + pref - v;
    carry += tot;
  }
  if (lane == 0) bucketTotal[b] = carry;
}

// ---------- partition pass 2b: exclusive scan of bucket totals ----------
__global__ __launch_bounds__(64) void k_scanB(const int* __restrict__ bucketTotal, int NB,
    int* __restrict__ bucketBase){
  int lane = threadIdx.x;
  int carry = 0;
  for (int r = 0; r*64 < NB; ++r){
    int idx = r*64 + lane;
    int v = (idx < NB) ? bucketTotal[idx] : 0;
    int pref = v;
    #pragma unroll
    for (int off = 1; off < 64; off <<= 1){ int t = __shfl_up(pref, off); if (lane >= off) pref += t; }
    int tot = __shfl(pref, 63);
    if (idx < NB) bucketBase[idx] = carry + pref - v;
    carry += tot;
  }
}

// ---------- partition pass 3: scatter into bucket-grouped edge array ----------
// entry = src | (d & 511) << 23   (src < 2^23)
__global__ __launch_bounds__(256) void k_scatter(const int* __restrict__ src,
    const int* __restrict__ dst, int E, int NB,
    const int* __restrict__ gHist, const int* __restrict__ bucketBase,
    uint32_t* __restrict__ edgesP){
  __shared__ int lpos[MAXNB];
  int blk = blockIdx.x;
  for (int i = threadIdx.x; i < NB; i += 256) lpos[i] = 0;
  __syncthreads();
  int chunk = (E + GPART - 1) / GPART;
  int e0 = blk * chunk, e1 = min(E, e0 + chunk);
  for (int e = e0 + threadIdx.x; e < e1; e += 256){
    int s = src[e], d = dst[e];
    int b = d >> BSHIFT;
    int o = atomicAdd(&lpos[b], 1);
    int pos = bucketBase[b] + gHist[b*GPART + blk] + o;
    edgesP[pos] = (uint32_t)s | ((uint32_t)(d & (BSIZE-1)) << 23);
  }
}

// ---------- CSR pass1: per-bucket count/scan -> start,cnt,dinv ----------
__global__ __launch_bounds__(256) void k_csr_p1(const uint32_t* __restrict__ edgesP,
    const int* __restrict__ bucketBase, const int* __restrict__ bucketTotal,
    int n, int* __restrict__ start, int* __restrict__ cnt, float* __restrict__ dinv){
  __shared__ int cnt_l[BSIZE], start_l[BSIZE];
  int b = blockIdx.x;
  int base = bucketBase[b], total = bucketTotal[b];
  int d0 = b << BSHIFT;
  int tid = threadIdx.x;
  for (int i = tid; i < BSIZE; i += 256) cnt_l[i] = 0;
  __syncthreads();
  for (int i = tid; i < total; i += 256)
    atomicAdd(&cnt_l[edgesP[base + i] >> 23], 1);
  __syncthreads();
  if (tid < 64){
    int lane = tid, carry = 0;
    #pragma unroll
    for (int r = 0; r < BSIZE/64; ++r){
      int v = cnt_l[r*64 + lane];
      int pref = v;
      #pragma unroll
      for (int off = 1; off < 64; off <<= 1){ int t = __shfl_up(pref, off); if (lane >= off) pref += t; }
      int tot = __shfl(pref, 63);
      start_l[r*64 + lane] = carry + pref - v;
      carry += tot;
    }
  }
  __syncthreads();
  for (int i = tid; i < BSIZE; i += 256){
    int d = d0 + i;
    if (d < n){
      int c = cnt_l[i];
      cnt[d] = c;
      start[d] = base + start_l[i];
      dinv[d] = rsqrtf((float)(c + 1));
    }
  }
}

// ---------- CSR pass2: place edges as (src, weight_bits) ----------
__global__ __launch_bounds__(256) void k_csr_p2(const uint32_t* __restrict__ edgesP,
    const int* __restrict__ bucketBase, const int* __restrict__ bucketTotal,
    const int* __restrict__ start, const float* __restrict__ dinv,
    int2* __restrict__ csr){
  __shared__ int fp[BSIZE];
  int b = blockIdx.x;
  int base = bucketBase[b], total = bucketTotal[b];
  int d0 = b << BSHIFT;
  int tid = threadIdx.x;
  for (int i = tid; i < BSIZE; i += 256) fp[i] = 0;
  __syncthreads();
  for (int i = tid; i < total; i += 256){
    uint32_t w = edgesP[base + i];
    int dl = (int)(w >> 23);
    int s = (int)(w & 0x7FFFFFu);
    int p = atomicAdd(&fp[dl], 1);
    float wt = dinv[s] * dinv[d0 + dl];
    csr[start[d0 + dl] + p] = make_int2(s, __float_as_int(wt));
  }
}

// ---------- weight pre-pack: W[K][Nc] f32 -> bf16 MFMA B-fragments ----------
__global__ __launch_bounds__(256) void k_packW(const float* __restrict__ W,
    uint4* __restrict__ Wf, int K, int Nc){
  int s = blockIdx.x * 256 + threadIdx.x;
  int total = (K >> 5) * (Nc >> 4) * 64;
  if (s >= total) return;
  int lane = s & 63;
  int frag = s >> 6;
  int NT = Nc >> 4;
  int nt = frag % NT, ks = frag / NT;
  int col = nt*16 + (lane & 15);
  int k0  = ks*32 + (lane >> 4)*8;
  float v[8];
  #pragma unroll
  for (int e = 0; e < 8; ++e) v[e] = W[(size_t)(k0 + e)*Nc + col];
  uint4 u;
  u.x = pack2bf(v[0], v[1]); u.y = pack2bf(v[2], v[3]);
  u.z = pack2bf(v[4], v[5]); u.w = pack2bf(v[6], v[7]);
  Wf[s] = u;
}

// ---------- GEMM1 (MFMA): H1[N,128](bf16) = bf16(X[N,256]) @ bf16(W1) ----------
// N-SPLIT: 2 waves per 16-row block, each owning 4 of the 8 column fragments.
// 12500 waves (12.2/SIMD supply); low VGPR (no W buffering -> TLP covers L2 lat);
// X prefetched 2 K-steps ahead. Pair-waves read identical X rows -> 2nd is L2-hit.
__global__ __launch_bounds__(256) void k_gemm1_mfma(const float* __restrict__ X,
    const uint4* __restrict__ W1f, unsigned short* __restrict__ H1, int n){
  int gw = (int)((blockIdx.x * 256u + threadIdx.x) >> 6);
  int lane = threadIdx.x & 63;
  int nh = gw & 1;              // column half
  int row0 = (gw >> 1) * 16;
  if (row0 >= n) return;
  int rA = lane & 15, kg = lane >> 4;
  f32x4 acc[4];
  #pragma unroll
  for (int nt = 0; nt < 4; ++nt) acc[nt] = (f32x4){0.f, 0.f, 0.f, 0.f};
  int r0 = min(row0 + rA, n - 1);
  const float* x0 = X + (size_t)r0*256 + kg*8;
  float4 fa[2], fb[2];
  fa[0] = *(const float4*)(x0);
  fb[0] = *(const float4*)(x0 + 4);
  fa[1] = *(const float4*)(x0 + 32);
  fb[1] = *(const float4*)(x0 + 36);
  #pragma unroll
  for (int ks = 0; ks < 8; ++ks){
    const int c = ks & 1;
    U4S8 a;
    a.u.x = pack2bf(fa[c].x, fa[c].y); a.u.y = pack2bf(fa[c].z, fa[c].w);
    a.u.z = pack2bf(fb[c].x, fb[c].y); a.u.w = pack2bf(fb[c].z, fb[c].w);
    if (ks < 6){
      fa[c] = *(const float4*)(x0 + (ks+2)*32);
      fb[c] = *(const float4*)(x0 + (ks+2)*32 + 4);
    }
    #pragma unroll
    for (int nt = 0; nt < 4; ++nt){
      U4S8 b; b.u = W1f[(ks*8 + nh*4 + nt)*64 + lane];
      acc[nt] = __builtin_amdgcn_mfma_f32_16x16x32_bf16(a.s, b.s, acc[nt], 0, 0, 0);
    }
  }
  #pragma unroll
  for (int r = 0; r < 4; ++r){
    int row = row0 + kg*4 + r;
    if (row < n){
      #pragma unroll
      for (int nt = 0; nt < 4; ++nt)
        H1[(size_t)row*128 + (nh*4 + nt)*16 + rA] = (unsigned short)f2bf_bits(acc[nt][r]);
    }
  }
}

// ---------- agg1: A1 = leakyrelu(Ahat @ H1 + b1)  (bf16 out) ----------
// one wave per node; 4 edge-groups x 16 lanes; lane li holds dims [8li,8li+8).
__global__ __launch_bounds__(256) void k_agg1(const uint4* __restrict__ H1,
    const int2* __restrict__ csr,
    const int* __restrict__ start, const int* __restrict__ cnt,
    const float* __restrict__ dinv, const float* __restrict__ b1,
    uint4* __restrict__ A1, int n){
  int w = (int)((blockIdx.x * blockDim.x + threadIdx.x) >> 6);
  int lane = threadIdx.x & 63;
  if (w >= n) return;
  int g = lane >> 4, li = lane & 15;
  float dw = dinv[w];
  float sw = (g == 0) ? dw * dw : 0.f;   // self-loop only counted by group 0
  uint4 hs = H1[(size_t)w*16 + li];
  float acc[8];
  acc[0]=sw*bflo(hs.x); acc[1]=sw*bfhi(hs.x); acc[2]=sw*bflo(hs.y); acc[3]=sw*bfhi(hs.y);
  acc[4]=sw*bflo(hs.z); acc[5]=sw*bfhi(hs.z); acc[6]=sw*bflo(hs.w); acc[7]=sw*bfhi(hs.w);
  int e0 = start[w], deg = cnt[w];
  for (int base = 0; base < deg; base += 64){
    int nin = min(64, deg - base);
    int2 ew = (lane < nin) ? csr[e0 + base + lane] : make_int2(0, 0);  // wt=0 pad
    for (int j = 0; j < nin; j += 8){
      int   sA = __shfl(ew.x, j + g);
      float wA = __uint_as_float((uint32_t)__shfl(ew.y, j + g));
      int   sB = __shfl(ew.x, j + 4 + g);
      float wB = __uint_as_float((uint32_t)__shfl(ew.y, j + 4 + g));
      uint4 hA = H1[(size_t)sA*16 + li];
      uint4 hB = H1[(size_t)sB*16 + li];
      acc[0]=fmaf(wA,bflo(hA.x),acc[0]); acc[1]=fmaf(wA,bfhi(hA.x),acc[1]);
      acc[2]=fmaf(wA,bflo(hA.y),acc[2]); acc[3]=fmaf(wA,bfhi(hA.y),acc[3]);
      acc[4]=fmaf(wA,bflo(hA.z),acc[4]); acc[5]=fmaf(wA,bfhi(hA.z),acc[5]);
      acc[6]=fmaf(wA,bflo(hA.w),acc[6]); acc[7]=fmaf(wA,bfhi(hA.w),acc[7]);
      acc[0]=fmaf(wB,bflo(hB.x),acc[0]); acc[1]=fmaf(wB,bfhi(hB.x),acc[1]);
      acc[2]=fmaf(wB,bflo(hB.y),acc[2]); acc[3]=fmaf(wB,bfhi(hB.y),acc[3]);
      acc[4]=fmaf(wB,bflo(hB.z),acc[4]); acc[5]=fmaf(wB,bfhi(hB.z),acc[5]);
      acc[6]=fmaf(wB,bflo(hB.w),acc[6]); acc[7]=fmaf(wB,bfhi(hB.w),acc[7]);
    }
  }
  #pragma unroll
  for (int e = 0; e < 8; ++e){
    acc[e] += __shfl_xor(acc[e], 16);
    acc[e] += __shfl_xor(acc[e], 32);
  }
  float4 bA = *(const float4*)&b1[li*8];
  float4 bB = *(const float4*)&b1[li*8 + 4];
  acc[0]+=bA.x; acc[1]+=bA.y; acc[2]+=bA.z; acc[3]+=bA.w;
  acc[4]+=bB.x; acc[5]+=bB.y; acc[6]+=bB.z; acc[7]+=bB.w;
  #pragma unroll
  for (int e = 0; e < 8; ++e) acc[e] = (acc[e] >= 0.f) ? acc[e] : 0.01f * acc[e];
  if (g == 0){
    uint4 o;
    o.x = pack2bf(acc[0], acc[1]); o.y = pack2bf(acc[2], acc[3]);
    o.z = pack2bf(acc[4], acc[5]); o.w = pack2bf(acc[6], acc[7]);
    A1[(size_t)w*16 + li] = o;
  }
}

// ---------- GEMM2 (MFMA): H2[N,64](bf16) = A1[N,128](bf16) @ bf16(W2) ----------
// N-SPLIT: 2 waves per 16-row block, each owning 2 of the 4 column fragments.
__global__ __launch_bounds__(256) void k_gemm2_mfma(const uint4* __restrict__ A1,
    const uint4* __restrict__ W2f, unsigned short* __restrict__ H2, int n){
  int gw = (int)((blockIdx.x * 256u + threadIdx.x) >> 6);
  int lane = threadIdx.x & 63;
  int nh = gw & 1;
  int row0 = (gw >> 1) * 16;
  if (row0 >= n) return;
  int rA = lane & 15, kg = lane >> 4;
  f32x4 acc[2];
  acc[0] = (f32x4){0.f, 0.f, 0.f, 0.f};
  acc[1] = (f32x4){0.f, 0.f, 0.f, 0.f};
  int r0 = min(row0 + rA, n - 1);
  const uint4* arow = A1 + (size_t)r0*16 + kg;
  uint4 u = arow[0];
  #pragma unroll
  for (int ks = 0; ks < 4; ++ks){
    U4S8 a; a.u = u;
    if (ks < 3) u = arow[(ks+1)*4];
    #pragma unroll
    for (int nt = 0; nt < 2; ++nt){
      U4S8 b; b.u = W2f[(ks*4 + nh*2 + nt)*64 + lane];
      acc[nt] = __builtin_amdgcn_mfma_f32_16x16x32_bf16(a.s, b.s, acc[nt], 0, 0, 0);
    }
  }
  #pragma unroll
  for (int r = 0; r < 4; ++r){
    int row = row0 + kg*4 + r;
    if (row < n){
      #pragma unroll
      for (int nt = 0; nt < 2; ++nt)
        H2[(size_t)row*64 + (nh*2 + nt)*16 + rA] = (unsigned short)f2bf_bits(acc[nt][r]);
    }
  }
}

// ---------- agg2: out = Ahat @ H2 + b2  (f32 out) ----------
// one wave per node; 8 edge-groups x 8 lanes; lane li holds dims [8li,8li+8).
__global__ __launch_bounds__(256) void k_agg2(const uint4* __restrict__ H2,
    const int2* __restrict__ csr,
    const int* __restrict__ start, const int* __restrict__ cnt,
    const float* __restrict__ dinv, const float* __restrict__ b2,
    float* __restrict__ out, int n){
  int w = (int)((blockIdx.x * blockDim.x + threadIdx.x) >> 6);
  int lane = threadIdx.x & 63;
  if (w >= n) return;
  int g = lane >> 3, li = lane & 7;
  float dw = dinv[w];
  float sw = (g == 0) ? dw * dw : 0.f;
  uint4 hs = H2[(size_t)w*8 + li];
  float acc[8];
  acc[0]=sw*bflo(hs.x); acc[1]=sw*bfhi(hs.x); acc[2]=sw*bflo(hs.y); acc[3]=sw*bfhi(hs.y);
  acc[4]=sw*bflo(hs.z); acc[5]=sw*bfhi(hs.z); acc[6]=sw*bflo(hs.w); acc[7]=sw*bfhi(hs.w);
  int e0 = start[w], deg = cnt[w];
  for (int base = 0; base < deg; base += 64){
    int nin = min(64, deg - base);
    int2 ew = (lane < nin) ? csr[e0 + base + lane] : make_int2(0, 0);
    for (int j = 0; j < nin; j += 16){
      int   sA = __shfl(ew.x, j + g);
      float wA = __uint_as_float((uint32_t)__shfl(ew.y, j + g));
      int   sB = __shfl(ew.x, j + 8 + g);
      float wB = __uint_as_float((uint32_t)__shfl(ew.y, j + 8 + g));
      uint4 hA = H2[(size_t)sA*8 + li];
      uint4 hB = H2[(size_t)sB*8 + li];
      acc[0]=fmaf(wA,bflo(hA.x),acc[0]); acc[1]=fmaf(wA,bfhi(hA.x),acc[1]);
      acc[2]=fmaf(wA,bflo(hA.y),acc[2]); acc[3]=fmaf(wA,bfhi(hA.y),acc[3]);
      acc[4]=fmaf(wA,bflo(hA.z),acc[4]); acc[5]=fmaf(wA,bfhi(hA.z),acc[5]);
      acc[6]=fmaf(wA,bflo(hA.w),acc[6]); acc[7]=fmaf(wA,bfhi(hA.w),acc[7]);
      acc[0]=fmaf(wB,bflo(hB.x),acc[0]); acc[1]=fmaf(wB,bfhi(hB.x),acc[1]);
      acc[2]=fmaf(wB,bflo(hB.y),acc[2]); acc[3]=fmaf(wB,bfhi(hB.y),acc[3]);
      acc[4]=fmaf(wB,bflo(hB.z),acc[4]); acc[5]=fmaf(wB,bfhi(hB.z),acc[5]);
      acc[6]=fmaf(wB,bflo(hB.w),acc[6]); acc[7]=fmaf(wB,bfhi(hB.w),acc[7]);
    }
  }
  #pragma unroll
  for (int e = 0; e < 8; ++e){
    acc[e] += __shfl_xor(acc[e], 8);
    acc[e] += __shfl_xor(acc[e], 16);
    acc[e] += __shfl_xor(acc[e], 32);
  }
  float4 bA = *(const float4*)&b2[li*8];
  float4 bB = *(const float4*)&b2[li*8 + 4];
  acc[0]+=bA.x; acc[1]+=bA.y; acc[2]+=bA.z; acc[3]+=bA.w;
  acc[4]+=bB.x; acc[5]+=bB.y; acc[6]+=bB.z; acc[7]+=bB.w;
  if (g == 0){
    float4 o0 = make_float4(acc[0], acc[1], acc[2], acc[3]);
    float4 o1 = make_float4(acc[4], acc[5], acc[6], acc[7]);
    *(float4*)&out[(size_t)w*64 + li*8]     = o0;
    *(float4*)&out[(size_t)w*64 + li*8 + 4] = o1;
  }
}

extern "C" void kernel_launch(void* const* d_in, const int* in_sizes, int n_in,
                              void* d_out, int out_size, void* d_ws, size_t ws_size,
                              hipStream_t stream){
  const float* x  = (const float*)d_in[0];
  const int*   ei = (const int*)d_in[1];   // [2,E] int32
  const float* W1 = (const float*)d_in[2];
  const float* b1 = (const float*)d_in[3];
  const float* W2 = (const float*)d_in[4];
  const float* b2 = (const float*)d_in[5];
  float* out = (float*)d_out;

  int N = in_sizes[0] / 256;
  int E = in_sizes[1] / 2;
  int NB = (N + BSIZE - 1) >> BSHIFT;

  char* p = (char*)d_ws;
  uint32_t* H1   = (uint32_t*)p;  p += (size_t)N*64*4;    // [N,128] bf16
  uint32_t* A1   = (uint32_t*)p;  p += (size_t)N*64*4;    // [N,128] bf16
  uint32_t* H2   = (uint32_t*)p;  p += (size_t)N*32*4;    // [N,64]  bf16
  uint32_t* edgesP=(uint32_t*)p;  p += (size_t)E*4;       // bucket-grouped edges
  int2* csr      = (int2*)p;      p += (size_t)E*8;       // (src, wt_bits) CSR
  int* gHist     = (int*)p;       p += (size_t)NB*GPART*4;
  int* bucketTotal=(int*)p;       p += (size_t)((NB+63)&~63)*4;
  int* bucketBase= (int*)p;       p += (size_t)((NB+63)&~63)*4;
  uint4* W1f     = (uint4*)p;     p += 8*8*64*16;         // 64 KB
  uint4* W2f     = (uint4*)p;     p += 4*4*64*16;         // 16 KB
  int* start     = (int*)p;       p += (size_t)N*4;
  int* cnt       = (int*)p;       p += (size_t)N*4;
  float* dinv    = (float*)p;     p += (size_t)N*4;

  const int* srcIdx = ei;
  const int* dstIdx = ei + E;

  int nW1 = ((N + 15) / 16) * 2;             // 2 waves per 16-row block
  int nBlocks1 = (nW1 + 3) / 4;
  int nNodeBlocks = (N + 3) / 4;             // 1 wave per node

  k_packW<<<(8*8*64 + 255)/256, 256, 0, stream>>>(W1, W1f, 256, 128);
  k_packW<<<(4*4*64 + 255)/256, 256, 0, stream>>>(W2, W2f, 128, 64);
  k_hist<<<GPART, 256, 0, stream>>>(dstIdx, E, NB, gHist);
  k_scanA<<<NB, 64, 0, stream>>>(gHist, bucketTotal);
  k_scanB<<<1, 64, 0, stream>>>(bucketTotal, NB, bucketBase);
  k_scatter<<<GPART, 256, 0, stream>>>(srcIdx, dstIdx, E, NB, gHist, bucketBase, edgesP);
  k_csr_p1<<<NB, 256, 0, stream>>>(edgesP, bucketBase, bucketTotal, N, start, cnt, dinv);
  k_csr_p2<<<NB, 256, 0, stream>>>(edgesP, bucketBase, bucketTotal, start, dinv, csr);
  k_gemm1_mfma<<<nBlocks1, 256, 0, stream>>>(x, W1f, (unsigned short*)H1, N);
  k_agg1<<<nNodeBlocks, 256, 0, stream>>>((const uint4*)H1, csr, start, cnt, dinv, b1, (uint4*)A1, N);
  k_gemm2_mfma<<<nBlocks1, 256, 0, stream>>>((const uint4*)A1, W2f, (unsigned short*)H2, N);
  k_agg2<<<nNodeBlocks, 256, 0, stream>>>((const uint4*)H2, csr, start, cnt, dinv, b2, out, N);
}

// Round 11
// 216.334 us; speedup vs baseline: 1.0504x; 1.0504x over previous
//
#include <hip/hip_runtime.h>
#include <hip/hip_bf16.h>
#include <stdint.h>

#define GPART 512      // partition grid blocks
#define BSHIFT 9
#define BSIZE 512      // nodes per bucket
#define MAXNB 512      // LDS histogram capacity (N up to 262144)

typedef short short8 __attribute__((ext_vector_type(8)));
typedef float f32x4 __attribute__((ext_vector_type(4)));
union U4S8 { uint4 u; short8 s; };

// ---------- bf16 helpers (raw-bits; RNE pack) ----------
static __device__ __forceinline__ float bflo(uint32_t h){ return __uint_as_float(h << 16); }
static __device__ __forceinline__ float bfhi(uint32_t h){ return __uint_as_float(h & 0xFFFF0000u); }
static __device__ __forceinline__ uint32_t f2bf_bits(float f){
  uint32_t u = __float_as_uint(f);
  return (u + 0x7FFFu + ((u >> 16) & 1u)) >> 16;
}
static __device__ __forceinline__ uint32_t pack2bf(float lo, float hi){
  return f2bf_bits(lo) | (f2bf_bits(hi) << 16);
}

// ---------- partition pass 1: per-(block,bucket) histogram ----------
__global__ __launch_bounds__(256) void k_hist(const int* __restrict__ dst, int E, int NB,
    int* __restrict__ gHist){
  __shared__ int lh[MAXNB];
  int blk = blockIdx.x;
  for (int i = threadIdx.x; i < NB; i += 256) lh[i] = 0;
  __syncthreads();
  int chunk = (E + GPART - 1) / GPART;
  int e0 = blk * chunk, e1 = min(E, e0 + chunk);
  for (int e = e0 + threadIdx.x; e < e1; e += 256)
    atomicAdd(&lh[dst[e] >> BSHIFT], 1);
  __syncthreads();
  for (int i = threadIdx.x; i < NB; i += 256) gHist[i * GPART + blk] = lh[i];
}

// ---------- partition pass 2a: scan block counts within each bucket ----------
__global__ __launch_bounds__(64) void k_scanA(int* __restrict__ gHist,
    int* __restrict__ bucketTotal){
  int b = blockIdx.x;
  int lane = threadIdx.x;
  int carry = 0;
  #pragma unroll
  for (int r = 0; r < GPART/64; ++r){
    int v = gHist[b*GPART + r*64 + lane];
    int pref = v;
    #pragma unroll
    for (int off = 1; off < 64; off <<= 1){ int t = __shfl_up(pref, off); if (lane >= off) pref += t; }
    int tot = __shfl(pref, 63);
    gHist[b*GPART + r*64 + lane] = carry + pref - v;
    carry += tot;
  }
  if (lane == 0) bucketTotal[b] = carry;
}

// ---------- partition pass 2b: exclusive scan of bucket totals ----------
__global__ __launch_bounds__(64) void k_scanB(const int* __restrict__ bucketTotal, int NB,
    int* __restrict__ bucketBase){
  int lane = threadIdx.x;
  int carry = 0;
  for (int r = 0; r*64 < NB; ++r){
    int idx = r*64 + lane;
    int v = (idx < NB) ? bucketTotal[idx] : 0;
    int pref = v;
    #pragma unroll
    for (int off = 1; off < 64; off <<= 1){ int t = __shfl_up(pref, off); if (lane >= off) pref += t; }
    int tot = __shfl(pref, 63);
    if (idx < NB) bucketBase[idx] = carry + pref - v;
    carry += tot;
  }
}

// ---------- partition pass 3: scatter into bucket-grouped edge array ----------
// entry = src | (d & 511) << 23   (src < 2^23)
__global__ __launch_bounds__(256) void k_scatter(const int* __restrict__ src,
    const int* __restrict__ dst, int E, int NB,
    const int* __restrict__ gHist, const int* __restrict__ bucketBase,
    uint32_t* __restrict__ edgesP){
  __shared__ int lpos[MAXNB];
  int blk = blockIdx.x;
  for (int i = threadIdx.x; i < NB; i += 256) lpos[i] = 0;
  __syncthreads();
  int chunk = (E + GPART - 1) / GPART;
  int e0 = blk * chunk, e1 = min(E, e0 + chunk);
  for (int e = e0 + threadIdx.x; e < e1; e += 256){
    int s = src[e], d = dst[e];
    int b = d >> BSHIFT;
    int o = atomicAdd(&lpos[b], 1);
    int pos = bucketBase[b] + gHist[b*GPART + blk] + o;
    edgesP[pos] = (uint32_t)s | ((uint32_t)(d & (BSIZE-1)) << 23);
  }
}

// ---------- CSR pass1: per-bucket count/scan -> start,cnt,dinv ----------
__global__ __launch_bounds__(256) void k_csr_p1(const uint32_t* __restrict__ edgesP,
    const int* __restrict__ bucketBase, const int* __restrict__ bucketTotal,
    int n, int* __restrict__ start, int* __restrict__ cnt, float* __restrict__ dinv){
  __shared__ int cnt_l[BSIZE], start_l[BSIZE];
  int b = blockIdx.x;
  int base = bucketBase[b], total = bucketTotal[b];
  int d0 = b << BSHIFT;
  int tid = threadIdx.x;
  for (int i = tid; i < BSIZE; i += 256) cnt_l[i] = 0;
  __syncthreads();
  for (int i = tid; i < total; i += 256)
    atomicAdd(&cnt_l[edgesP[base + i] >> 23], 1);
  __syncthreads();
  if (tid < 64){
    int lane = tid, carry = 0;
    #pragma unroll
    for (int r = 0; r < BSIZE/64; ++r){
      int v = cnt_l[r*64 + lane];
      int pref = v;
      #pragma unroll
      for (int off = 1; off < 64; off <<= 1){ int t = __shfl_up(pref, off); if (lane >= off) pref += t; }
      int tot = __shfl(pref, 63);
      start_l[r*64 + lane] = carry + pref - v;
      carry += tot;
    }
  }
  __syncthreads();
  for (int i = tid; i < BSIZE; i += 256){
    int d = d0 + i;
    if (d < n){
      int c = cnt_l[i];
      cnt[d] = c;
      start[d] = base + start_l[i];
      dinv[d] = rsqrtf((float)(c + 1));
    }
  }
}

// ---------- CSR pass2: place edges as (src, weight_bits) ----------
__global__ __launch_bounds__(256) void k_csr_p2(const uint32_t* __restrict__ edgesP,
    const int* __restrict__ bucketBase, const int* __restrict__ bucketTotal,
    const int* __restrict__ start, const float* __restrict__ dinv,
    int2* __restrict__ csr){
  __shared__ int fp[BSIZE];
  int b = blockIdx.x;
  int base = bucketBase[b], total = bucketTotal[b];
  int d0 = b << BSHIFT;
  int tid = threadIdx.x;
  for (int i = tid; i < BSIZE; i += 256) fp[i] = 0;
  __syncthreads();
  for (int i = tid; i < total; i += 256){
    uint32_t w = edgesP[base + i];
    int dl = (int)(w >> 23);
    int s = (int)(w & 0x7FFFFFu);
    int p = atomicAdd(&fp[dl], 1);
    float wt = dinv[s] * dinv[d0 + dl];
    csr[start[d0 + dl] + p] = make_int2(s, __float_as_int(wt));
  }
}

// ---------- weight pre-pack: W[K][Nc] f32 -> bf16 MFMA B-fragments ----------
__global__ __launch_bounds__(256) void k_packW(const float* __restrict__ W,
    uint4* __restrict__ Wf, int K, int Nc){
  int s = blockIdx.x * 256 + threadIdx.x;
  int total = (K >> 5) * (Nc >> 4) * 64;
  if (s >= total) return;
  int lane = s & 63;
  int frag = s >> 6;
  int NT = Nc >> 4;
  int nt = frag % NT, ks = frag / NT;
  int col = nt*16 + (lane & 15);
  int k0  = ks*32 + (lane >> 4)*8;
  float v[8];
  #pragma unroll
  for (int e = 0; e < 8; ++e) v[e] = W[(size_t)(k0 + e)*Nc + col];
  uint4 u;
  u.x = pack2bf(v[0], v[1]); u.y = pack2bf(v[2], v[3]);
  u.z = pack2bf(v[4], v[5]); u.w = pack2bf(v[6], v[7]);
  Wf[s] = u;
}

// ---------- GEMM1 (MFMA, LDS-staged): H1[N,128] = bf16(X[N,256]) @ bf16(W1) ----------
// Block = 4 waves, 32-row x K=256 X tile staged via global_load_lds width=16
// (one instr = one 1KB row; source pre-swizzled granule = lane ^ (r&7); LDS dest
// linear per m104/m173). 32 KB LDS -> 5 blocks/CU co-resident for overlap.
// Wave (mhalf,nh) computes a 16-row x 64-col quadrant; acc[4].
__global__ __launch_bounds__(256) void k_gemm1_lds(const float* __restrict__ X,
    const uint4* __restrict__ W1f, unsigned short* __restrict__ H1, int n){
  __shared__ float xs[32][256];          // 32 KB
  int tid = threadIdx.x;
  int wid = tid >> 6, lane = tid & 63;
  int row0 = blockIdx.x * 32;
  // ---- stage: each wave DMAs 8 rows (8 x 1KB), swizzled source ----
  #pragma unroll
  for (int i = 0; i < 8; ++i){
    int r = wid*8 + i;
    int gr = min(row0 + r, n - 1);
    const float* gsrc = X + (size_t)gr*256 + 4*(lane ^ (r & 7));
    __builtin_amdgcn_global_load_lds(
        (const __attribute__((address_space(1))) unsigned int*)gsrc,
        (__attribute__((address_space(3))) unsigned int*)(&xs[r][0]),
        16, 0, 0);
  }
  __syncthreads();
  // ---- compute ----
  int mhalf = wid & 1, nh = wid >> 1;
  int rA = lane & 15, kg = lane >> 4;
  int lrow = mhalf*16 + rA;
  f32x4 acc[4];
  #pragma unroll
  for (int nt = 0; nt < 4; ++nt) acc[nt] = (f32x4){0.f, 0.f, 0.f, 0.f};
  #pragma unroll
  for (int ks = 0; ks < 8; ++ks){
    int g0 = ks*8 + kg*2;
    float4 f0 = *(const float4*)&xs[lrow][4*( g0      ^ (rA & 7))];
    float4 f1 = *(const float4*)&xs[lrow][4*((g0 + 1) ^ (rA & 7))];
    U4S8 a;
    a.u.x = pack2bf(f0.x, f0.y); a.u.y = pack2bf(f0.z, f0.w);
    a.u.z = pack2bf(f1.x, f1.y); a.u.w = pack2bf(f1.z, f1.w);
    #pragma unroll
    for (int nt = 0; nt < 4; ++nt){
      U4S8 b; b.u = W1f[(ks*8 + nh*4 + nt)*64 + lane];
      acc[nt] = __builtin_amdgcn_mfma_f32_16x16x32_bf16(a.s, b.s, acc[nt], 0, 0, 0);
    }
  }
  int rowbase = row0 + mhalf*16 + kg*4;
  #pragma unroll
  for (int r = 0; r < 4; ++r){
    int row = rowbase + r;
    if (row < n){
      #pragma unroll
      for (int nt = 0; nt < 4; ++nt)
        H1[(size_t)row*128 + (nh*4 + nt)*16 + rA] = (unsigned short)f2bf_bits(acc[nt][r]);
    }
  }
}

// ---------- agg1: A1 = leakyrelu(Ahat @ H1 + b1)  (bf16 out) ----------
// one wave per node; 4 edge-groups x 16 lanes; lane li holds dims [8li,8li+8).
__global__ __launch_bounds__(256) void k_agg1(const uint4* __restrict__ H1,
    const int2* __restrict__ csr,
    const int* __restrict__ start, const int* __restrict__ cnt,
    const float* __restrict__ dinv, const float* __restrict__ b1,
    uint4* __restrict__ A1, int n){
  int w = (int)((blockIdx.x * blockDim.x + threadIdx.x) >> 6);
  int lane = threadIdx.x & 63;
  if (w >= n) return;
  int g = lane >> 4, li = lane & 15;
  float dw = dinv[w];
  float sw = (g == 0) ? dw * dw : 0.f;   // self-loop only counted by group 0
  uint4 hs = H1[(size_t)w*16 + li];
  float acc[8];
  acc[0]=sw*bflo(hs.x); acc[1]=sw*bfhi(hs.x); acc[2]=sw*bflo(hs.y); acc[3]=sw*bfhi(hs.y);
  acc[4]=sw*bflo(hs.z); acc[5]=sw*bfhi(hs.z); acc[6]=sw*bflo(hs.w); acc[7]=sw*bfhi(hs.w);
  int e0 = start[w], deg = cnt[w];
  for (int base = 0; base < deg; base += 64){
    int nin = min(64, deg - base);
    int2 ew = (lane < nin) ? csr[e0 + base + lane] : make_int2(0, 0);  // wt=0 pad
    for (int j = 0; j < nin; j += 8){
      int   sA = __shfl(ew.x, j + g);
      float wA = __uint_as_float((uint32_t)__shfl(ew.y, j + g));
      int   sB = __shfl(ew.x, j + 4 + g);
      float wB = __uint_as_float((uint32_t)__shfl(ew.y, j + 4 + g));
      uint4 hA = H1[(size_t)sA*16 + li];
      uint4 hB = H1[(size_t)sB*16 + li];
      acc[0]=fmaf(wA,bflo(hA.x),acc[0]); acc[1]=fmaf(wA,bfhi(hA.x),acc[1]);
      acc[2]=fmaf(wA,bflo(hA.y),acc[2]); acc[3]=fmaf(wA,bfhi(hA.y),acc[3]);
      acc[4]=fmaf(wA,bflo(hA.z),acc[4]); acc[5]=fmaf(wA,bfhi(hA.z),acc[5]);
      acc[6]=fmaf(wA,bflo(hA.w),acc[6]); acc[7]=fmaf(wA,bfhi(hA.w),acc[7]);
      acc[0]=fmaf(wB,bflo(hB.x),acc[0]); acc[1]=fmaf(wB,bfhi(hB.x),acc[1]);
      acc[2]=fmaf(wB,bflo(hB.y),acc[2]); acc[3]=fmaf(wB,bfhi(hB.y),acc[3]);
      acc[4]=fmaf(wB,bflo(hB.z),acc[4]); acc[5]=fmaf(wB,bfhi(hB.z),acc[5]);
      acc[6]=fmaf(wB,bflo(hB.w),acc[6]); acc[7]=fmaf(wB,bfhi(hB.w),acc[7]);
    }
  }
  #pragma unroll
  for (int e = 0; e < 8; ++e){
    acc[e] += __shfl_xor(acc[e], 16);
    acc[e] += __shfl_xor(acc[e], 32);
  }
  float4 bA = *(const float4*)&b1[li*8];
  float4 bB = *(const float4*)&b1[li*8 + 4];
  acc[0]+=bA.x; acc[1]+=bA.y; acc[2]+=bA.z; acc[3]+=bA.w;
  acc[4]+=bB.x; acc[5]+=bB.y; acc[6]+=bB.z; acc[7]+=bB.w;
  #pragma unroll
  for (int e = 0; e < 8; ++e) acc[e] = (acc[e] >= 0.f) ? acc[e] : 0.01f * acc[e];
  if (g == 0){
    uint4 o;
    o.x = pack2bf(acc[0], acc[1]); o.y = pack2bf(acc[2], acc[3]);
    o.z = pack2bf(acc[4], acc[5]); o.w = pack2bf(acc[6], acc[7]);
    A1[(size_t)w*16 + li] = o;
  }
}

// ---------- GEMM2 (MFMA): H2[N,64](bf16) = A1[N,128](bf16) @ bf16(W2) ----------
// one wave per 16 rows; A-frags stream directly from global with 1-deep prefetch.
__global__ __launch_bounds__(256) void k_gemm2_mfma(const uint4* __restrict__ A1,
    const uint4* __restrict__ W2f, unsigned short* __restrict__ H2, int n){
  int wv = (int)((blockIdx.x * 256u + threadIdx.x) >> 6);
  int lane = threadIdx.x & 63;
  int row0 = wv * 16;
  if (row0 >= n) return;
  int rA = lane & 15, kg = lane >> 4;
  f32x4 acc[4];
  #pragma unroll
  for (int nt = 0; nt < 4; ++nt) acc[nt] = (f32x4){0.f, 0.f, 0.f, 0.f};
  int r0 = min(row0 + rA, n - 1);
  const uint4* arow = A1 + (size_t)r0*16 + kg;
  uint4 u = arow[0];
  #pragma unroll
  for (int ks = 0; ks < 4; ++ks){
    U4S8 a; a.u = u;
    if (ks < 3) u = arow[(ks+1)*4];
    #pragma unroll
    for (int nt = 0; nt < 4; ++nt){
      U4S8 b; b.u = W2f[(ks*4 + nt)*64 + lane];
      acc[nt] = __builtin_amdgcn_mfma_f32_16x16x32_bf16(a.s, b.s, acc[nt], 0, 0, 0);
    }
  }
  #pragma unroll
  for (int r = 0; r < 4; ++r){
    int row = row0 + kg*4 + r;
    if (row < n){
      #pragma unroll
      for (int nt = 0; nt < 4; ++nt)
        H2[(size_t)row*64 + nt*16 + rA] = (unsigned short)f2bf_bits(acc[nt][r]);
    }
  }
}

// ---------- agg2: out = Ahat @ H2 + b2  (f32 out) ----------
// one wave per node; 8 edge-groups x 8 lanes; lane li holds dims [8li,8li+8).
__global__ __launch_bounds__(256) void k_agg2(const uint4* __restrict__ H2,
    const int2* __restrict__ csr,
    const int* __restrict__ start, const int* __restrict__ cnt,
    const float* __restrict__ dinv, const float* __restrict__ b2,
    float* __restrict__ out, int n){
  int w = (int)((blockIdx.x * blockDim.x + threadIdx.x) >> 6);
  int lane = threadIdx.x & 63;
  if (w >= n) return;
  int g = lane >> 3, li = lane & 7;
  float dw = dinv[w];
  float sw = (g == 0) ? dw * dw : 0.f;
  uint4 hs = H2[(size_t)w*8 + li];
  float acc[8];
  acc[0]=sw*bflo(hs.x); acc[1]=sw*bfhi(hs.x); acc[2]=sw*bflo(hs.y); acc[3]=sw*bfhi(hs.y);
  acc[4]=sw*bflo(hs.z); acc[5]=sw*bfhi(hs.z); acc[6]=sw*bflo(hs.w); acc[7]=sw*bfhi(hs.w);
  int e0 = start[w], deg = cnt[w];
  for (int base = 0; base < deg; base += 64){
    int nin = min(64, deg - base);
    int2 ew = (lane < nin) ? csr[e0 + base + lane] : make_int2(0, 0);
    for (int j = 0; j < nin; j += 16){
      int   sA = __shfl(ew.x, j + g);
      float wA = __uint_as_float((uint32_t)__shfl(ew.y, j + g));
      int   sB = __shfl(ew.x, j + 8 + g);
      float wB = __uint_as_float((uint32_t)__shfl(ew.y, j + 8 + g));
      uint4 hA = H2[(size_t)sA*8 + li];
      uint4 hB = H2[(size_t)sB*8 + li];
      acc[0]=fmaf(wA,bflo(hA.x),acc[0]); acc[1]=fmaf(wA,bfhi(hA.x),acc[1]);
      acc[2]=fmaf(wA,bflo(hA.y),acc[2]); acc[3]=fmaf(wA,bfhi(hA.y),acc[3]);
      acc[4]=fmaf(wA,bflo(hA.z),acc[4]); acc[5]=fmaf(wA,bfhi(hA.z),acc[5]);
      acc[6]=fmaf(wA,bflo(hA.w),acc[6]); acc[7]=fmaf(wA,bfhi(hA.w),acc[7]);
      acc[0]=fmaf(wB,bflo(hB.x),acc[0]); acc[1]=fmaf(wB,bfhi(hB.x),acc[1]);
      acc[2]=fmaf(wB,bflo(hB.y),acc[2]); acc[3]=fmaf(wB,bfhi(hB.y),acc[3]);
      acc[4]=fmaf(wB,bflo(hB.z),acc[4]); acc[5]=fmaf(wB,bfhi(hB.z),acc[5]);
      acc[6]=fmaf(wB,bflo(hB.w),acc[6]); acc[7]=fmaf(wB,bfhi(hB.w),acc[7]);
    }
  }
  #pragma unroll
  for (int e = 0; e < 8; ++e){
    acc[e] += __shfl_xor(acc[e], 8);
    acc[e] += __shfl_xor(acc[e], 16);
    acc[e] += __shfl_xor(acc[e], 32);
  }
  float4 bA = *(const float4*)&b2[li*8];
  float4 bB = *(const float4*)&b2[li*8 + 4];
  acc[0]+=bA.x; acc[1]+=bA.y; acc[2]+=bA.z; acc[3]+=bA.w;
  acc[4]+=bB.x; acc[5]+=bB.y; acc[6]+=bB.z; acc[7]+=bB.w;
  if (g == 0){
    float4 o0 = make_float4(acc[0], acc[1], acc[2], acc[3]);
    float4 o1 = make_float4(acc[4], acc[5], acc[6], acc[7]);
    *(float4*)&out[(size_t)w*64 + li*8]     = o0;
    *(float4*)&out[(size_t)w*64 + li*8 + 4] = o1;
  }
}

extern "C" void kernel_launch(void* const* d_in, const int* in_sizes, int n_in,
                              void* d_out, int out_size, void* d_ws, size_t ws_size,
                              hipStream_t stream){
  const float* x  = (const float*)d_in[0];
  const int*   ei = (const int*)d_in[1];   // [2,E] int32
  const float* W1 = (const float*)d_in[2];
  const float* b1 = (const float*)d_in[3];
  const float* W2 = (const float*)d_in[4];
  const float* b2 = (const float*)d_in[5];
  float* out = (float*)d_out;

  int N = in_sizes[0] / 256;
  int E = in_sizes[1] / 2;
  int NB = (N + BSIZE - 1) >> BSHIFT;

  char* p = (char*)d_ws;
  uint32_t* H1   = (uint32_t*)p;  p += (size_t)N*64*4;    // [N,128] bf16
  uint32_t* A1   = (uint32_t*)p;  p += (size_t)N*64*4;    // [N,128] bf16
  uint32_t* H2   = (uint32_t*)p;  p += (size_t)N*32*4;    // [N,64]  bf16
  uint32_t* edgesP=(uint32_t*)p;  p += (size_t)E*4;       // bucket-grouped edges
  int2* csr      = (int2*)p;      p += (size_t)E*8;       // (src, wt_bits) CSR
  int* gHist     = (int*)p;       p += (size_t)NB*GPART*4;
  int* bucketTotal=(int*)p;       p += (size_t)((NB+63)&~63)*4;
  int* bucketBase= (int*)p;       p += (size_t)((NB+63)&~63)*4;
  uint4* W1f     = (uint4*)p;     p += 8*8*64*16;         // 64 KB
  uint4* W2f     = (uint4*)p;     p += 4*4*64*16;         // 16 KB
  int* start     = (int*)p;       p += (size_t)N*4;
  int* cnt       = (int*)p;       p += (size_t)N*4;
  float* dinv    = (float*)p;     p += (size_t)N*4;

  const int* srcIdx = ei;
  const int* dstIdx = ei + E;

  int nG1Blocks = (N + 31) / 32;             // 32-row LDS tile per block
  int nW2 = (N + 15) / 16;                   // gemm2: 1 wave per 16 rows
  int nG2Blocks = (nW2 + 3) / 4;
  int nNodeBlocks = (N + 3) / 4;             // aggs: 1 wave per node

  k_packW<<<(8*8*64 + 255)/256, 256, 0, stream>>>(W1, W1f, 256, 128);
  k_packW<<<(4*4*64 + 255)/256, 256, 0, stream>>>(W2, W2f, 128, 64);
  k_hist<<<GPART, 256, 0, stream>>>(dstIdx, E, NB, gHist);
  k_scanA<<<NB, 64, 0, stream>>>(gHist, bucketTotal);
  k_scanB<<<1, 64, 0, stream>>>(bucketTotal, NB, bucketBase);
  k_scatter<<<GPART, 256, 0, stream>>>(srcIdx, dstIdx, E, NB, gHist, bucketBase, edgesP);
  k_csr_p1<<<NB, 256, 0, stream>>>(edgesP, bucketBase, bucketTotal, N, start, cnt, dinv);
  k_csr_p2<<<NB, 256, 0, stream>>>(edgesP, bucketBase, bucketTotal, start, dinv, csr);
  k_gemm1_lds<<<nG1Blocks, 256, 0, stream>>>(x, W1f, (unsigned short*)H1, N);
  k_agg1<<<nNodeBlocks, 256, 0, stream>>>((const uint4*)H1, csr, start, cnt, dinv, b1, (uint4*)A1, N);
  k_gemm2_mfma<<<nG2Blocks, 256, 0, stream>>>((const uint4*)A1, W2f, (unsigned short*)H2, N);
  k_agg2<<<nNodeBlocks, 256, 0, stream>>>((const uint4*)H2, csr, start, cnt, dinv, b2, out, N);
}

// Round 12
// 212.387 us; speedup vs baseline: 1.0699x; 1.0186x over previous
//
#include <hip/hip_runtime.h>
#include <hip/hip_bf16.h>
#include <stdint.h>

#define GPART 512      // partition grid blocks
#define BSHIFT 9
#define BSIZE 512      // nodes per bucket
#define MAXNB 512      // LDS histogram capacity (N up to 262144)

typedef short short8 __attribute__((ext_vector_type(8)));
typedef float f32x4 __attribute__((ext_vector_type(4)));
union U4S8 { uint4 u; short8 s; };

// ---------- bf16 helpers (raw-bits; RNE pack) ----------
static __device__ __forceinline__ float bflo(uint32_t h){ return __uint_as_float(h << 16); }
static __device__ __forceinline__ float bfhi(uint32_t h){ return __uint_as_float(h & 0xFFFF0000u); }
static __device__ __forceinline__ uint32_t f2bf_bits(float f){
  uint32_t u = __float_as_uint(f);
  return (u + 0x7FFFu + ((u >> 16) & 1u)) >> 16;
}
static __device__ __forceinline__ uint32_t pack2bf(float lo, float hi){
  return f2bf_bits(lo) | (f2bf_bits(hi) << 16);
}

// ---------- gemm1 tile as a device function (32 rows, LDS-staged via global_load_lds) ----------
// smem must be >= 32 KB. Co-scheduled inside the build "fat" kernels.
static __device__ __forceinline__ void gemm1_tile(const float* __restrict__ X,
    const uint4* __restrict__ W1f, unsigned short* __restrict__ H1, int n,
    int row0, char* smem, int tid){
  float (*xs)[256] = (float (*)[256])smem;
  int wid = tid >> 6, lane = tid & 63;
  #pragma unroll
  for (int i = 0; i < 8; ++i){
    int r = wid*8 + i;
    int gr = min(row0 + r, n - 1);
    const float* gsrc = X + (size_t)gr*256 + 4*(lane ^ (r & 7));
    __builtin_amdgcn_global_load_lds(
        (const __attribute__((address_space(1))) unsigned int*)gsrc,
        (__attribute__((address_space(3))) unsigned int*)(&xs[r][0]),
        16, 0, 0);
  }
  __syncthreads();
  int mhalf = wid & 1, nh = wid >> 1;
  int rA = lane & 15, kg = lane >> 4;
  int lrow = mhalf*16 + rA;
  f32x4 acc[4];
  #pragma unroll
  for (int nt = 0; nt < 4; ++nt) acc[nt] = (f32x4){0.f, 0.f, 0.f, 0.f};
  #pragma unroll
  for (int ks = 0; ks < 8; ++ks){
    int g0 = ks*8 + kg*2;
    float4 f0 = *(const float4*)&xs[lrow][4*( g0      ^ (rA & 7))];
    float4 f1 = *(const float4*)&xs[lrow][4*((g0 + 1) ^ (rA & 7))];
    U4S8 a;
    a.u.x = pack2bf(f0.x, f0.y); a.u.y = pack2bf(f0.z, f0.w);
    a.u.z = pack2bf(f1.x, f1.y); a.u.w = pack2bf(f1.z, f1.w);
    #pragma unroll
    for (int nt = 0; nt < 4; ++nt){
      U4S8 b; b.u = W1f[(ks*8 + nh*4 + nt)*64 + lane];
      acc[nt] = __builtin_amdgcn_mfma_f32_16x16x32_bf16(a.s, b.s, acc[nt], 0, 0, 0);
    }
  }
  int rowbase = row0 + mhalf*16 + kg*4;
  #pragma unroll
  for (int r = 0; r < 4; ++r){
    int row = rowbase + r;
    if (row < n){
      #pragma unroll
      for (int nt = 0; nt < 4; ++nt)
        H1[(size_t)row*128 + (nh*4 + nt)*16 + rA] = (unsigned short)f2bf_bits(acc[nt][r]);
    }
  }
}

// ---------- FAT kernel 1: histogram  ∪  gemm1 slice ----------
__global__ __launch_bounds__(256) void k_fat_hist(const int* __restrict__ dst, int E, int NB,
    int* __restrict__ gHist,
    const float* __restrict__ X, const uint4* __restrict__ W1f,
    unsigned short* __restrict__ H1, int n, int g1base, int nbuild){
  __shared__ __align__(16) char smem[32768];
  int tid = threadIdx.x;
  if ((int)blockIdx.x >= nbuild){
    int row0 = (g1base + (int)blockIdx.x - nbuild) * 32;
    gemm1_tile(X, W1f, H1, n, row0, smem, tid);
    return;
  }
  int* lh = (int*)smem;
  int blk = blockIdx.x;
  for (int i = tid; i < NB; i += 256) lh[i] = 0;
  __syncthreads();
  int chunk = (E + GPART - 1) / GPART;
  int e0 = blk * chunk, e1 = min(E, e0 + chunk);
  for (int e = e0 + tid; e < e1; e += 256)
    atomicAdd(&lh[dst[e] >> BSHIFT], 1);
  __syncthreads();
  for (int i = tid; i < NB; i += 256) gHist[i * GPART + blk] = lh[i];
}

// ---------- partition pass 2a: scan block counts within each bucket ----------
__global__ __launch_bounds__(64) void k_scanA(int* __restrict__ gHist,
    int* __restrict__ bucketTotal){
  int b = blockIdx.x;
  int lane = threadIdx.x;
  int carry = 0;
  #pragma unroll
  for (int r = 0; r < GPART/64; ++r){
    int v = gHist[b*GPART + r*64 + lane];
    int pref = v;
    #pragma unroll
    for (int off = 1; off < 64; off <<= 1){ int t = __shfl_up(pref, off); if (lane >= off) pref += t; }
    int tot = __shfl(pref, 63);
    gHist[b*GPART + r*64 + lane] = carry + pref - v;
    carry += tot;
  }
  if (lane == 0) bucketTotal[b] = carry;
}

// ---------- partition pass 2b: exclusive scan of bucket totals ----------
__global__ __launch_bounds__(64) void k_scanB(const int* __restrict__ bucketTotal, int NB,
    int* __restrict__ bucketBase){
  int lane = threadIdx.x;
  int carry = 0;
  for (int r = 0; r*64 < NB; ++r){
    int idx = r*64 + lane;
    int v = (idx < NB) ? bucketTotal[idx] : 0;
    int pref = v;
    #pragma unroll
    for (int off = 1; off < 64; off <<= 1){ int t = __shfl_up(pref, off); if (lane >= off) pref += t; }
    int tot = __shfl(pref, 63);
    if (idx < NB) bucketBase[idx] = carry + pref - v;
    carry += tot;
  }
}

// ---------- FAT kernel 2: scatter  ∪  gemm1 slice ----------
// entry = src | (d & 511) << 23   (src < 2^23)
__global__ __launch_bounds__(256) void k_fat_scatter(const int* __restrict__ src,
    const int* __restrict__ dst, int E, int NB,
    const int* __restrict__ gHist, const int* __restrict__ bucketBase,
    uint32_t* __restrict__ edgesP,
    const float* __restrict__ X, const uint4* __restrict__ W1f,
    unsigned short* __restrict__ H1, int n, int g1base, int nbuild){
  __shared__ __align__(16) char smem[32768];
  int tid = threadIdx.x;
  if ((int)blockIdx.x >= nbuild){
    int row0 = (g1base + (int)blockIdx.x - nbuild) * 32;
    gemm1_tile(X, W1f, H1, n, row0, smem, tid);
    return;
  }
  int* lpos = (int*)smem;
  int blk = blockIdx.x;
  for (int i = tid; i < NB; i += 256) lpos[i] = 0;
  __syncthreads();
  int chunk = (E + GPART - 1) / GPART;
  int e0 = blk * chunk, e1 = min(E, e0 + chunk);
  for (int e = e0 + tid; e < e1; e += 256){
    int s = src[e], d = dst[e];
    int b = d >> BSHIFT;
    int o = atomicAdd(&lpos[b], 1);
    int pos = bucketBase[b] + gHist[b*GPART + blk] + o;
    edgesP[pos] = (uint32_t)s | ((uint32_t)(d & (BSIZE-1)) << 23);
  }
}

// ---------- FAT kernel 3: CSR pass1  ∪  gemm1 slice ----------
__global__ __launch_bounds__(256) void k_fat_p1(const uint32_t* __restrict__ edgesP,
    const int* __restrict__ bucketBase, const int* __restrict__ bucketTotal,
    int n, int* __restrict__ start, int* __restrict__ cnt, float* __restrict__ dinv,
    const float* __restrict__ X, const uint4* __restrict__ W1f,
    unsigned short* __restrict__ H1, int g1base, int nbuild){
  __shared__ __align__(16) char smem[32768];
  int tid = threadIdx.x;
  if ((int)blockIdx.x >= nbuild){
    int row0 = (g1base + (int)blockIdx.x - nbuild) * 32;
    gemm1_tile(X, W1f, H1, n, row0, smem, tid);
    return;
  }
  int* cnt_l   = (int*)smem;
  int* start_l = (int*)(smem + BSIZE*4);
  int b = blockIdx.x;
  int base = bucketBase[b], total = bucketTotal[b];
  int d0 = b << BSHIFT;
  for (int i = tid; i < BSIZE; i += 256) cnt_l[i] = 0;
  __syncthreads();
  for (int i = tid; i < total; i += 256)
    atomicAdd(&cnt_l[edgesP[base + i] >> 23], 1);
  __syncthreads();
  if (tid < 64){
    int lane = tid, carry = 0;
    #pragma unroll
    for (int r = 0; r < BSIZE/64; ++r){
      int v = cnt_l[r*64 + lane];
      int pref = v;
      #pragma unroll
      for (int off = 1; off < 64; off <<= 1){ int t = __shfl_up(pref, off); if (lane >= off) pref += t; }
      int tot = __shfl(pref, 63);
      start_l[r*64 + lane] = carry + pref - v;
      carry += tot;
    }
  }
  __syncthreads();
  for (int i = tid; i < BSIZE; i += 256){
    int d = d0 + i;
    if (d < n){
      int c = cnt_l[i];
      cnt[d] = c;
      start[d] = base + start_l[i];
      dinv[d] = rsqrtf((float)(c + 1));
    }
  }
}

// ---------- FAT kernel 4: CSR pass2  ∪  gemm1 slice ----------
__global__ __launch_bounds__(256) void k_fat_p2(const uint32_t* __restrict__ edgesP,
    const int* __restrict__ bucketBase, const int* __restrict__ bucketTotal,
    const int* __restrict__ start, const float* __restrict__ dinv,
    int2* __restrict__ csr,
    const float* __restrict__ X, const uint4* __restrict__ W1f,
    unsigned short* __restrict__ H1, int n, int g1base, int nbuild){
  __shared__ __align__(16) char smem[32768];
  int tid = threadIdx.x;
  if ((int)blockIdx.x >= nbuild){
    int row0 = (g1base + (int)blockIdx.x - nbuild) * 32;
    gemm1_tile(X, W1f, H1, n, row0, smem, tid);
    return;
  }
  int* fp = (int*)smem;
  int b = blockIdx.x;
  int base = bucketBase[b], total = bucketTotal[b];
  int d0 = b << BSHIFT;
  for (int i = tid; i < BSIZE; i += 256) fp[i] = 0;
  __syncthreads();
  for (int i = tid; i < total; i += 256){
    uint32_t w = edgesP[base + i];
    int dl = (int)(w >> 23);
    int s = (int)(w & 0x7FFFFFu);
    int p = atomicAdd(&fp[dl], 1);
    float wt = dinv[s] * dinv[d0 + dl];
    csr[start[d0 + dl] + p] = make_int2(s, __float_as_int(wt));
  }
}

// ---------- weight pre-pack: W[K][Nc] f32 -> bf16 MFMA B-fragments ----------
__global__ __launch_bounds__(256) void k_packW(const float* __restrict__ W,
    uint4* __restrict__ Wf, int K, int Nc){
  int s = blockIdx.x * 256 + threadIdx.x;
  int total = (K >> 5) * (Nc >> 4) * 64;
  if (s >= total) return;
  int lane = s & 63;
  int frag = s >> 6;
  int NT = Nc >> 4;
  int nt = frag % NT, ks = frag / NT;
  int col = nt*16 + (lane & 15);
  int k0  = ks*32 + (lane >> 4)*8;
  float v[8];
  #pragma unroll
  for (int e = 0; e < 8; ++e) v[e] = W[(size_t)(k0 + e)*Nc + col];
  uint4 u;
  u.x = pack2bf(v[0], v[1]); u.y = pack2bf(v[2], v[3]);
  u.z = pack2bf(v[4], v[5]); u.w = pack2bf(v[6], v[7]);
  Wf[s] = u;
}

// ---------- agg1: A1 = leakyrelu(Ahat @ H1 + b1)  (bf16 out) ----------
__global__ __launch_bounds__(256) void k_agg1(const uint4* __restrict__ H1,
    const int2* __restrict__ csr,
    const int* __restrict__ start, const int* __restrict__ cnt,
    const float* __restrict__ dinv, const float* __restrict__ b1,
    uint4* __restrict__ A1, int n){
  int w = (int)((blockIdx.x * blockDim.x + threadIdx.x) >> 6);
  int lane = threadIdx.x & 63;
  if (w >= n) return;
  int g = lane >> 4, li = lane & 15;
  float dw = dinv[w];
  float sw = (g == 0) ? dw * dw : 0.f;   // self-loop only counted by group 0
  uint4 hs = H1[(size_t)w*16 + li];
  float acc[8];
  acc[0]=sw*bflo(hs.x); acc[1]=sw*bfhi(hs.x); acc[2]=sw*bflo(hs.y); acc[3]=sw*bfhi(hs.y);
  acc[4]=sw*bflo(hs.z); acc[5]=sw*bfhi(hs.z); acc[6]=sw*bflo(hs.w); acc[7]=sw*bfhi(hs.w);
  int e0 = start[w], deg = cnt[w];
  for (int base = 0; base < deg; base += 64){
    int nin = min(64, deg - base);
    int2 ew = (lane < nin) ? csr[e0 + base + lane] : make_int2(0, 0);  // wt=0 pad
    for (int j = 0; j < nin; j += 8){
      int   sA = __shfl(ew.x, j + g);
      float wA = __uint_as_float((uint32_t)__shfl(ew.y, j + g));
      int   sB = __shfl(ew.x, j + 4 + g);
      float wB = __uint_as_float((uint32_t)__shfl(ew.y, j + 4 + g));
      uint4 hA = H1[(size_t)sA*16 + li];
      uint4 hB = H1[(size_t)sB*16 + li];
      acc[0]=fmaf(wA,bflo(hA.x),acc[0]); acc[1]=fmaf(wA,bfhi(hA.x),acc[1]);
      acc[2]=fmaf(wA,bflo(hA.y),acc[2]); acc[3]=fmaf(wA,bfhi(hA.y),acc[3]);
      acc[4]=fmaf(wA,bflo(hA.z),acc[4]); acc[5]=fmaf(wA,bfhi(hA.z),acc[5]);
      acc[6]=fmaf(wA,bflo(hA.w),acc[6]); acc[7]=fmaf(wA,bfhi(hA.w),acc[7]);
      acc[0]=fmaf(wB,bflo(hB.x),acc[0]); acc[1]=fmaf(wB,bfhi(hB.x),acc[1]);
      acc[2]=fmaf(wB,bflo(hB.y),acc[2]); acc[3]=fmaf(wB,bfhi(hB.y),acc[3]);
      acc[4]=fmaf(wB,bflo(hB.z),acc[4]); acc[5]=fmaf(wB,bfhi(hB.z),acc[5]);
      acc[6]=fmaf(wB,bflo(hB.w),acc[6]); acc[7]=fmaf(wB,bfhi(hB.w),acc[7]);
    }
  }
  #pragma unroll
  for (int e = 0; e < 8; ++e){
    acc[e] += __shfl_xor(acc[e], 16);
    acc[e] += __shfl_xor(acc[e], 32);
  }
  float4 bA = *(const float4*)&b1[li*8];
  float4 bB = *(const float4*)&b1[li*8 + 4];
  acc[0]+=bA.x; acc[1]+=bA.y; acc[2]+=bA.z; acc[3]+=bA.w;
  acc[4]+=bB.x; acc[5]+=bB.y; acc[6]+=bB.z; acc[7]+=bB.w;
  #pragma unroll
  for (int e = 0; e < 8; ++e) acc[e] = (acc[e] >= 0.f) ? acc[e] : 0.01f * acc[e];
  if (g == 0){
    uint4 o;
    o.x = pack2bf(acc[0], acc[1]); o.y = pack2bf(acc[2], acc[3]);
    o.z = pack2bf(acc[4], acc[5]); o.w = pack2bf(acc[6], acc[7]);
    A1[(size_t)w*16 + li] = o;
  }
}

// ---------- GEMM2 (MFMA): H2[N,64](bf16) = A1[N,128](bf16) @ bf16(W2) ----------
__global__ __launch_bounds__(256) void k_gemm2_mfma(const uint4* __restrict__ A1,
    const uint4* __restrict__ W2f, unsigned short* __restrict__ H2, int n){
  int wv = (int)((blockIdx.x * 256u + threadIdx.x) >> 6);
  int lane = threadIdx.x & 63;
  int row0 = wv * 16;
  if (row0 >= n) return;
  int rA = lane & 15, kg = lane >> 4;
  f32x4 acc[4];
  #pragma unroll
  for (int nt = 0; nt < 4; ++nt) acc[nt] = (f32x4){0.f, 0.f, 0.f, 0.f};
  int r0 = min(row0 + rA, n - 1);
  const uint4* arow = A1 + (size_t)r0*16 + kg;
  uint4 u = arow[0];
  #pragma unroll
  for (int ks = 0; ks < 4; ++ks){
    U4S8 a; a.u = u;
    if (ks < 3) u = arow[(ks+1)*4];
    #pragma unroll
    for (int nt = 0; nt < 4; ++nt){
      U4S8 b; b.u = W2f[(ks*4 + nt)*64 + lane];
      acc[nt] = __builtin_amdgcn_mfma_f32_16x16x32_bf16(a.s, b.s, acc[nt], 0, 0, 0);
    }
  }
  #pragma unroll
  for (int r = 0; r < 4; ++r){
    int row = row0 + kg*4 + r;
    if (row < n){
      #pragma unroll
      for (int nt = 0; nt < 4; ++nt)
        H2[(size_t)row*64 + nt*16 + rA] = (unsigned short)f2bf_bits(acc[nt][r]);
    }
  }
}

// ---------- agg2: out = Ahat @ H2 + b2  (f32 out) ----------
__global__ __launch_bounds__(256) void k_agg2(const uint4* __restrict__ H2,
    const int2* __restrict__ csr,
    const int* __restrict__ start, const int* __restrict__ cnt,
    const float* __restrict__ dinv, const float* __restrict__ b2,
    float* __restrict__ out, int n){
  int w = (int)((blockIdx.x * blockDim.x + threadIdx.x) >> 6);
  int lane = threadIdx.x & 63;
  if (w >= n) return;
  int g = lane >> 3, li = lane & 7;
  float dw = dinv[w];
  float sw = (g == 0) ? dw * dw : 0.f;
  uint4 hs = H2[(size_t)w*8 + li];
  float acc[8];
  acc[0]=sw*bflo(hs.x); acc[1]=sw*bfhi(hs.x); acc[2]=sw*bflo(hs.y); acc[3]=sw*bfhi(hs.y);
  acc[4]=sw*bflo(hs.z); acc[5]=sw*bfhi(hs.z); acc[6]=sw*bflo(hs.w); acc[7]=sw*bfhi(hs.w);
  int e0 = start[w], deg = cnt[w];
  for (int base = 0; base < deg; base += 64){
    int nin = min(64, deg - base);
    int2 ew = (lane < nin) ? csr[e0 + base + lane] : make_int2(0, 0);
    for (int j = 0; j < nin; j += 16){
      int   sA = __shfl(ew.x, j + g);
      float wA = __uint_as_float((uint32_t)__shfl(ew.y, j + g));
      int   sB = __shfl(ew.x, j + 8 + g);
      float wB = __uint_as_float((uint32_t)__shfl(ew.y, j + 8 + g));
      uint4 hA = H2[(size_t)sA*8 + li];
      uint4 hB = H2[(size_t)sB*8 + li];
      acc[0]=fmaf(wA,bflo(hA.x),acc[0]); acc[1]=fmaf(wA,bfhi(hA.x),acc[1]);
      acc[2]=fmaf(wA,bflo(hA.y),acc[2]); acc[3]=fmaf(wA,bfhi(hA.y),acc[3]);
      acc[4]=fmaf(wA,bflo(hA.z),acc[4]); acc[5]=fmaf(wA,bfhi(hA.z),acc[5]);
      acc[6]=fmaf(wA,bflo(hA.w),acc[6]); acc[7]=fmaf(wA,bfhi(hA.w),acc[7]);
      acc[0]=fmaf(wB,bflo(hB.x),acc[0]); acc[1]=fmaf(wB,bfhi(hB.x),acc[1]);
      acc[2]=fmaf(wB,bflo(hB.y),acc[2]); acc[3]=fmaf(wB,bfhi(hB.y),acc[3]);
      acc[4]=fmaf(wB,bflo(hB.z),acc[4]); acc[5]=fmaf(wB,bfhi(hB.z),acc[5]);
      acc[6]=fmaf(wB,bflo(hB.w),acc[6]); acc[7]=fmaf(wB,bfhi(hB.w),acc[7]);
    }
  }
  #pragma unroll
  for (int e = 0; e < 8; ++e){
    acc[e] += __shfl_xor(acc[e], 8);
    acc[e] += __shfl_xor(acc[e], 16);
    acc[e] += __shfl_xor(acc[e], 32);
  }
  float4 bA = *(const float4*)&b2[li*8];
  float4 bB = *(const float4*)&b2[li*8 + 4];
  acc[0]+=bA.x; acc[1]+=bA.y; acc[2]+=bA.z; acc[3]+=bA.w;
  acc[4]+=bB.x; acc[5]+=bB.y; acc[6]+=bB.z; acc[7]+=bB.w;
  if (g == 0){
    float4 o0 = make_float4(acc[0], acc[1], acc[2], acc[3]);
    float4 o1 = make_float4(acc[4], acc[5], acc[6], acc[7]);
    *(float4*)&out[(size_t)w*64 + li*8]     = o0;
    *(float4*)&out[(size_t)w*64 + li*8 + 4] = o1;
  }
}

extern "C" void kernel_launch(void* const* d_in, const int* in_sizes, int n_in,
                              void* d_out, int out_size, void* d_ws, size_t ws_size,
                              hipStream_t stream){
  const float* x  = (const float*)d_in[0];
  const int*   ei = (const int*)d_in[1];   // [2,E] int32
  const float* W1 = (const float*)d_in[2];
  const float* b1 = (const float*)d_in[3];
  const float* W2 = (const float*)d_in[4];
  const float* b2 = (const float*)d_in[5];
  float* out = (float*)d_out;

  int N = in_sizes[0] / 256;
  int E = in_sizes[1] / 2;
  int NB = (N + BSIZE - 1) >> BSHIFT;

  char* p = (char*)d_ws;
  uint32_t* H1   = (uint32_t*)p;  p += (size_t)N*64*4;    // [N,128] bf16
  uint32_t* A1   = (uint32_t*)p;  p += (size_t)N*64*4;    // [N,128] bf16
  uint32_t* H2   = (uint32_t*)p;  p += (size_t)N*32*4;    // [N,64]  bf16
  uint32_t* edgesP=(uint32_t*)p;  p += (size_t)E*4;       // bucket-grouped edges
  int2* csr      = (int2*)p;      p += (size_t)E*8;       // (src, wt_bits) CSR
  int* gHist     = (int*)p;       p += (size_t)NB*GPART*4;
  int* bucketTotal=(int*)p;       p += (size_t)((NB+63)&~63)*4;
  int* bucketBase= (int*)p;       p += (size_t)((NB+63)&~63)*4;
  uint4* W1f     = (uint4*)p;     p += 8*8*64*16;         // 64 KB
  uint4* W2f     = (uint4*)p;     p += 4*4*64*16;         // 16 KB
  int* start     = (int*)p;       p += (size_t)N*4;
  int* cnt       = (int*)p;       p += (size_t)N*4;
  float* dinv    = (float*)p;     p += (size_t)N*4;

  const int* srcIdx = ei;
  const int* dstIdx = ei + E;

  unsigned short* H1u = (unsigned short*)H1;

  int G1 = (N + 31) / 32;                   // total gemm1 tiles (3125 @ N=100K)
  // slice sizes ~ proportional to build-kernel durations (hist:scatter:p1:p2 ~ 9:15:8:13)
  int sA = (int)((long)G1 * 20 / 100);
  int sB = (int)((long)G1 * 33 / 100);
  int sC = (int)((long)G1 * 18 / 100);
  int sD = G1 - sA - sB - sC;

  int nW2 = (N + 15) / 16;                  // gemm2: 1 wave per 16 rows
  int nG2Blocks = (nW2 + 3) / 4;
  int nNodeBlocks = (N + 3) / 4;            // aggs: 1 wave per node

  k_packW<<<(8*8*64 + 255)/256, 256, 0, stream>>>(W1, W1f, 256, 128);
  k_packW<<<(4*4*64 + 255)/256, 256, 0, stream>>>(W2, W2f, 128, 64);
  k_fat_hist<<<GPART + sA, 256, 0, stream>>>(dstIdx, E, NB, gHist,
      x, W1f, H1u, N, 0, GPART);
  k_scanA<<<NB, 64, 0, stream>>>(gHist, bucketTotal);
  k_scanB<<<1, 64, 0, stream>>>(bucketTotal, NB, bucketBase);
  k_fat_scatter<<<GPART + sB, 256, 0, stream>>>(srcIdx, dstIdx, E, NB, gHist, bucketBase,
      edgesP, x, W1f, H1u, N, sA, GPART);
  k_fat_p1<<<NB + sC, 256, 0, stream>>>(edgesP, bucketBase, bucketTotal, N, start, cnt, dinv,
      x, W1f, H1u, sA + sB, NB);
  k_fat_p2<<<NB + sD, 256, 0, stream>>>(edgesP, bucketBase, bucketTotal, start, dinv, csr,
      x, W1f, H1u, N, sA + sB + sC, NB);
  k_agg1<<<nNodeBlocks, 256, 0, stream>>>((const uint4*)H1, csr, start, cnt, dinv, b1, (uint4*)A1, N);
  k_gemm2_mfma<<<nG2Blocks, 256, 0, stream>>>((const uint4*)A1, W2f, (unsigned short*)H2, N);
  k_agg2<<<nNodeBlocks, 256, 0, stream>>>((const uint4*)H2, csr, start, cnt, dinv, b2, out, N);
}

// Round 13
// 201.003 us; speedup vs baseline: 1.1305x; 1.0566x over previous
//
#include <hip/hip_runtime.h>
#include <hip/hip_bf16.h>
#include <stdint.h>

#define GPART 512      // partition grid blocks
#define BSHIFT 9
#define BSIZE 512      // nodes per bucket
#define MAXNB 512      // LDS histogram capacity (N up to 262144)

typedef short short8 __attribute__((ext_vector_type(8)));
typedef float f32x4 __attribute__((ext_vector_type(4)));
union U4S8 { uint4 u; short8 s; };

// ---------- bf16 helpers (raw-bits; RNE pack) ----------
static __device__ __forceinline__ float bflo(uint32_t h){ return __uint_as_float(h << 16); }
static __device__ __forceinline__ float bfhi(uint32_t h){ return __uint_as_float(h & 0xFFFF0000u); }
static __device__ __forceinline__ uint32_t f2bf_bits(float f){
  uint32_t u = __float_as_uint(f);
  return (u + 0x7FFFu + ((u >> 16) & 1u)) >> 16;
}
static __device__ __forceinline__ uint32_t pack2bf(float lo, float hi){
  return f2bf_bits(lo) | (f2bf_bits(hi) << 16);
}

// ---------- gemm1 tile (32 rows, LDS-staged via global_load_lds) ----------
static __device__ __forceinline__ void gemm1_tile(const float* __restrict__ X,
    const uint4* __restrict__ W1f, unsigned short* __restrict__ H1, int n,
    int row0, char* smem, int tid){
  float (*xs)[256] = (float (*)[256])smem;
  int wid = tid >> 6, lane = tid & 63;
  #pragma unroll
  for (int i = 0; i < 8; ++i){
    int r = wid*8 + i;
    int gr = min(row0 + r, n - 1);
    const float* gsrc = X + (size_t)gr*256 + 4*(lane ^ (r & 7));
    __builtin_amdgcn_global_load_lds(
        (const __attribute__((address_space(1))) unsigned int*)gsrc,
        (__attribute__((address_space(3))) unsigned int*)(&xs[r][0]),
        16, 0, 0);
  }
  __syncthreads();
  int mhalf = wid & 1, nh = wid >> 1;
  int rA = lane & 15, kg = lane >> 4;
  int lrow = mhalf*16 + rA;
  f32x4 acc[4];
  #pragma unroll
  for (int nt = 0; nt < 4; ++nt) acc[nt] = (f32x4){0.f, 0.f, 0.f, 0.f};
  #pragma unroll
  for (int ks = 0; ks < 8; ++ks){
    int g0 = ks*8 + kg*2;
    float4 f0 = *(const float4*)&xs[lrow][4*( g0      ^ (rA & 7))];
    float4 f1 = *(const float4*)&xs[lrow][4*((g0 + 1) ^ (rA & 7))];
    U4S8 a;
    a.u.x = pack2bf(f0.x, f0.y); a.u.y = pack2bf(f0.z, f0.w);
    a.u.z = pack2bf(f1.x, f1.y); a.u.w = pack2bf(f1.z, f1.w);
    #pragma unroll
    for (int nt = 0; nt < 4; ++nt){
      U4S8 b; b.u = W1f[(ks*8 + nh*4 + nt)*64 + lane];
      acc[nt] = __builtin_amdgcn_mfma_f32_16x16x32_bf16(a.s, b.s, acc[nt], 0, 0, 0);
    }
  }
  int rowbase = row0 + mhalf*16 + kg*4;
  #pragma unroll
  for (int r = 0; r < 4; ++r){
    int row = rowbase + r;
    if (row < n){
      #pragma unroll
      for (int nt = 0; nt < 4; ++nt)
        H1[(size_t)row*128 + (nh*4 + nt)*16 + rA] = (unsigned short)f2bf_bits(acc[nt][r]);
    }
  }
}

// ---------- FAT kernel 1: histogram  ∪  gemm1 slice ----------
__global__ __launch_bounds__(256) void k_fat_hist(const int* __restrict__ dst, int E, int NB,
    int* __restrict__ gHist,
    const float* __restrict__ X, const uint4* __restrict__ W1f,
    unsigned short* __restrict__ H1, int n, int g1base, int nbuild){
  __shared__ __align__(16) char smem[32768];
  int tid = threadIdx.x;
  if ((int)blockIdx.x >= nbuild){
    int row0 = (g1base + (int)blockIdx.x - nbuild) * 32;
    gemm1_tile(X, W1f, H1, n, row0, smem, tid);
    return;
  }
  int* lh = (int*)smem;
  int blk = blockIdx.x;
  for (int i = tid; i < NB; i += 256) lh[i] = 0;
  __syncthreads();
  int chunk = (E + GPART - 1) / GPART;
  int e0 = blk * chunk, e1 = min(E, e0 + chunk);
  for (int e = e0 + tid; e < e1; e += 256)
    atomicAdd(&lh[dst[e] >> BSHIFT], 1);
  __syncthreads();
  for (int i = tid; i < NB; i += 256) gHist[i * GPART + blk] = lh[i];
}

// ---------- partition pass 2a: scan block counts within each bucket ----------
__global__ __launch_bounds__(64) void k_scanA(int* __restrict__ gHist,
    int* __restrict__ bucketTotal){
  int b = blockIdx.x;
  int lane = threadIdx.x;
  int carry = 0;
  #pragma unroll
  for (int r = 0; r < GPART/64; ++r){
    int v = gHist[b*GPART + r*64 + lane];
    int pref = v;
    #pragma unroll
    for (int off = 1; off < 64; off <<= 1){ int t = __shfl_up(pref, off); if (lane >= off) pref += t; }
    int tot = __shfl(pref, 63);
    gHist[b*GPART + r*64 + lane] = carry + pref - v;
    carry += tot;
  }
  if (lane == 0) bucketTotal[b] = carry;
}

// ---------- partition pass 2b: exclusive scan of bucket totals ----------
__global__ __launch_bounds__(64) void k_scanB(const int* __restrict__ bucketTotal, int NB,
    int* __restrict__ bucketBase){
  int lane = threadIdx.x;
  int carry = 0;
  for (int r = 0; r*64 < NB; ++r){
    int idx = r*64 + lane;
    int v = (idx < NB) ? bucketTotal[idx] : 0;
    int pref = v;
    #pragma unroll
    for (int off = 1; off < 64; off <<= 1){ int t = __shfl_up(pref, off); if (lane >= off) pref += t; }
    int tot = __shfl(pref, 63);
    if (idx < NB) bucketBase[idx] = carry + pref - v;
    carry += tot;
  }
}

// ---------- FAT kernel 2: scatter  ∪  gemm1 slice ----------
// entry = src | (d & 511) << 23   (src < 2^23)
__global__ __launch_bounds__(256) void k_fat_scatter(const int* __restrict__ src,
    const int* __restrict__ dst, int E, int NB,
    const int* __restrict__ gHist, const int* __restrict__ bucketBase,
    uint32_t* __restrict__ edgesP,
    const float* __restrict__ X, const uint4* __restrict__ W1f,
    unsigned short* __restrict__ H1, int n, int g1base, int nbuild){
  __shared__ __align__(16) char smem[32768];
  int tid = threadIdx.x;
  if ((int)blockIdx.x >= nbuild){
    int row0 = (g1base + (int)blockIdx.x - nbuild) * 32;
    gemm1_tile(X, W1f, H1, n, row0, smem, tid);
    return;
  }
  int* lpos = (int*)smem;
  int blk = blockIdx.x;
  for (int i = tid; i < NB; i += 256) lpos[i] = 0;
  __syncthreads();
  int chunk = (E + GPART - 1) / GPART;
  int e0 = blk * chunk, e1 = min(E, e0 + chunk);
  for (int e = e0 + tid; e < e1; e += 256){
    int s = src[e], d = dst[e];
    int b = d >> BSHIFT;
    int o = atomicAdd(&lpos[b], 1);
    int pos = bucketBase[b] + gHist[b*GPART + blk] + o;
    edgesP[pos] = (uint32_t)s | ((uint32_t)(d & (BSIZE-1)) << 23);
  }
}

// ---------- FAT kernel 3: merged CSR build (count+scan+place, ONE edgesP pass) ∪ gemm1 slice ----------
// CSR stores src only (4B/edge); weights derived in aggs via dinv gathers.
__global__ __launch_bounds__(256) void k_fat_p12(const uint32_t* __restrict__ edgesP,
    const int* __restrict__ bucketBase, const int* __restrict__ bucketTotal,
    int n, int* __restrict__ start, int* __restrict__ cnt, float* __restrict__ dinv,
    int* __restrict__ csr,
    const float* __restrict__ X, const uint4* __restrict__ W1f,
    unsigned short* __restrict__ H1, int g1base, int nbuild){
  __shared__ __align__(16) char smem[32768];
  int tid = threadIdx.x;
  if ((int)blockIdx.x >= nbuild){
    int row0 = (g1base + (int)blockIdx.x - nbuild) * 32;
    gemm1_tile(X, W1f, H1, n, row0, smem, tid);
    return;
  }
  int* cnt_l   = (int*)smem;                 // 512 ints
  int* start_l = (int*)(smem + 2048);        // 512 ints
  int* fp      = (int*)(smem + 4096);        // 512 ints
  int b = blockIdx.x;
  int base = bucketBase[b], total = bucketTotal[b];
  int d0 = b << BSHIFT;
  for (int i = tid; i < BSIZE; i += 256){ cnt_l[i] = 0; fp[i] = 0; }
  __syncthreads();
  for (int i = tid; i < total; i += 256)
    atomicAdd(&cnt_l[edgesP[base + i] >> 23], 1);
  __syncthreads();
  if (tid < 64){
    int lane = tid, carry = 0;
    #pragma unroll
    for (int r = 0; r < BSIZE/64; ++r){
      int v = cnt_l[r*64 + lane];
      int pref = v;
      #pragma unroll
      for (int off = 1; off < 64; off <<= 1){ int t = __shfl_up(pref, off); if (lane >= off) pref += t; }
      int tot = __shfl(pref, 63);
      start_l[r*64 + lane] = carry + pref - v;
      carry += tot;
    }
  }
  __syncthreads();
  for (int i = tid; i < BSIZE; i += 256){
    int d = d0 + i;
    if (d < n){
      int c = cnt_l[i];
      cnt[d] = c;
      start[d] = base + start_l[i];
      dinv[d] = rsqrtf((float)(c + 1));
    }
  }
  // placement pass: edgesP re-read is L2-hot (just streamed by the count pass)
  for (int i = tid; i < total; i += 256){
    uint32_t w = edgesP[base + i];
    int dl = (int)(w >> 23);
    int s = (int)(w & 0x7FFFFFu);
    int p = atomicAdd(&fp[dl], 1);
    csr[base + start_l[dl] + p] = s;
  }
}

// ---------- weight pre-pack: W[K][Nc] f32 -> bf16 MFMA B-fragments ----------
__global__ __launch_bounds__(256) void k_packW(const float* __restrict__ W,
    uint4* __restrict__ Wf, int K, int Nc){
  int s = blockIdx.x * 256 + threadIdx.x;
  int total = (K >> 5) * (Nc >> 4) * 64;
  if (s >= total) return;
  int lane = s & 63;
  int frag = s >> 6;
  int NT = Nc >> 4;
  int nt = frag % NT, ks = frag / NT;
  int col = nt*16 + (lane & 15);
  int k0  = ks*32 + (lane >> 4)*8;
  float v[8];
  #pragma unroll
  for (int e = 0; e < 8; ++e) v[e] = W[(size_t)(k0 + e)*Nc + col];
  uint4 u;
  u.x = pack2bf(v[0], v[1]); u.y = pack2bf(v[2], v[3]);
  u.z = pack2bf(v[4], v[5]); u.w = pack2bf(v[6], v[7]);
  Wf[s] = u;
}

// ---------- agg1: A1 = leakyrelu(Ahat @ H1 + b1)  (bf16 out) ----------
// one wave per node; 4 edge-groups x 16 lanes; src-only CSR, weight = dinv[s]*dinv[w].
__global__ __launch_bounds__(256) void k_agg1(const uint4* __restrict__ H1,
    const int* __restrict__ csr,
    const int* __restrict__ start, const int* __restrict__ cnt,
    const float* __restrict__ dinv, const float* __restrict__ b1,
    uint4* __restrict__ A1, int n){
  int w = (int)((blockIdx.x * blockDim.x + threadIdx.x) >> 6);
  int lane = threadIdx.x & 63;
  if (w >= n) return;
  int g = lane >> 4, li = lane & 15;
  float dw = dinv[w];
  float sw = (g == 0) ? dw * dw : 0.f;   // self-loop only counted by group 0
  uint4 hs = H1[(size_t)w*16 + li];
  float acc[8];
  acc[0]=sw*bflo(hs.x); acc[1]=sw*bfhi(hs.x); acc[2]=sw*bflo(hs.y); acc[3]=sw*bfhi(hs.y);
  acc[4]=sw*bflo(hs.z); acc[5]=sw*bfhi(hs.z); acc[6]=sw*bflo(hs.w); acc[7]=sw*bfhi(hs.w);
  int e0 = start[w], deg = cnt[w];
  for (int base = 0; base < deg; base += 64){
    int nin = min(64, deg - base);
    int sE = (lane < nin) ? csr[e0 + base + lane] : 0;
    float dvE = (lane < nin) ? dinv[sE] : 0.f;   // pad lanes -> weight 0
    for (int j = 0; j < nin; j += 8){
      int   sA = __shfl(sE, j + g);
      float wA = __shfl(dvE, j + g) * dw;
      int   sB = __shfl(sE, j + 4 + g);
      float wB = __shfl(dvE, j + 4 + g) * dw;
      uint4 hA = H1[(size_t)sA*16 + li];
      uint4 hB = H1[(size_t)sB*16 + li];
      acc[0]=fmaf(wA,bflo(hA.x),acc[0]); acc[1]=fmaf(wA,bfhi(hA.x),acc[1]);
      acc[2]=fmaf(wA,bflo(hA.y),acc[2]); acc[3]=fmaf(wA,bfhi(hA.y),acc[3]);
      acc[4]=fmaf(wA,bflo(hA.z),acc[4]); acc[5]=fmaf(wA,bfhi(hA.z),acc[5]);
      acc[6]=fmaf(wA,bflo(hA.w),acc[6]); acc[7]=fmaf(wA,bfhi(hA.w),acc[7]);
      acc[0]=fmaf(wB,bflo(hB.x),acc[0]); acc[1]=fmaf(wB,bfhi(hB.x),acc[1]);
      acc[2]=fmaf(wB,bflo(hB.y),acc[2]); acc[3]=fmaf(wB,bfhi(hB.y),acc[3]);
      acc[4]=fmaf(wB,bflo(hB.z),acc[4]); acc[5]=fmaf(wB,bfhi(hB.z),acc[5]);
      acc[6]=fmaf(wB,bflo(hB.w),acc[6]); acc[7]=fmaf(wB,bfhi(hB.w),acc[7]);
    }
  }
  #pragma unroll
  for (int e = 0; e < 8; ++e){
    acc[e] += __shfl_xor(acc[e], 16);
    acc[e] += __shfl_xor(acc[e], 32);
  }
  float4 bA = *(const float4*)&b1[li*8];
  float4 bB = *(const float4*)&b1[li*8 + 4];
  acc[0]+=bA.x; acc[1]+=bA.y; acc[2]+=bA.z; acc[3]+=bA.w;
  acc[4]+=bB.x; acc[5]+=bB.y; acc[6]+=bB.z; acc[7]+=bB.w;
  #pragma unroll
  for (int e = 0; e < 8; ++e) acc[e] = (acc[e] >= 0.f) ? acc[e] : 0.01f * acc[e];
  if (g == 0){
    uint4 o;
    o.x = pack2bf(acc[0], acc[1]); o.y = pack2bf(acc[2], acc[3]);
    o.z = pack2bf(acc[4], acc[5]); o.w = pack2bf(acc[6], acc[7]);
    A1[(size_t)w*16 + li] = o;
  }
}

// ---------- GEMM2 (MFMA): H2[N,64](bf16) = A1[N,128](bf16) @ bf16(W2) ----------
__global__ __launch_bounds__(256) void k_gemm2_mfma(const uint4* __restrict__ A1,
    const uint4* __restrict__ W2f, unsigned short* __restrict__ H2, int n){
  int wv = (int)((blockIdx.x * 256u + threadIdx.x) >> 6);
  int lane = threadIdx.x & 63;
  int row0 = wv * 16;
  if (row0 >= n) return;
  int rA = lane & 15, kg = lane >> 4;
  f32x4 acc[4];
  #pragma unroll
  for (int nt = 0; nt < 4; ++nt) acc[nt] = (f32x4){0.f, 0.f, 0.f, 0.f};
  int r0 = min(row0 + rA, n - 1);
  const uint4* arow = A1 + (size_t)r0*16 + kg;
  uint4 u = arow[0];
  #pragma unroll
  for (int ks = 0; ks < 4; ++ks){
    U4S8 a; a.u = u;
    if (ks < 3) u = arow[(ks+1)*4];
    #pragma unroll
    for (int nt = 0; nt < 4; ++nt){
      U4S8 b; b.u = W2f[(ks*4 + nt)*64 + lane];
      acc[nt] = __builtin_amdgcn_mfma_f32_16x16x32_bf16(a.s, b.s, acc[nt], 0, 0, 0);
    }
  }
  #pragma unroll
  for (int r = 0; r < 4; ++r){
    int row = row0 + kg*4 + r;
    if (row < n){
      #pragma unroll
      for (int nt = 0; nt < 4; ++nt)
        H2[(size_t)row*64 + nt*16 + rA] = (unsigned short)f2bf_bits(acc[nt][r]);
    }
  }
}

// ---------- agg2: out = Ahat @ H2 + b2  (f32 out) ----------
// one wave per node; 8 edge-groups x 8 lanes; src-only CSR.
__global__ __launch_bounds__(256) void k_agg2(const uint4* __restrict__ H2,
    const int* __restrict__ csr,
    const int* __restrict__ start, const int* __restrict__ cnt,
    const float* __restrict__ dinv, const float* __restrict__ b2,
    float* __restrict__ out, int n){
  int w = (int)((blockIdx.x * blockDim.x + threadIdx.x) >> 6);
  int lane = threadIdx.x & 63;
  if (w >= n) return;
  int g = lane >> 3, li = lane & 7;
  float dw = dinv[w];
  float sw = (g == 0) ? dw * dw : 0.f;
  uint4 hs = H2[(size_t)w*8 + li];
  float acc[8];
  acc[0]=sw*bflo(hs.x); acc[1]=sw*bfhi(hs.x); acc[2]=sw*bflo(hs.y); acc[3]=sw*bfhi(hs.y);
  acc[4]=sw*bflo(hs.z); acc[5]=sw*bfhi(hs.z); acc[6]=sw*bflo(hs.w); acc[7]=sw*bfhi(hs.w);
  int e0 = start[w], deg = cnt[w];
  for (int base = 0; base < deg; base += 64){
    int nin = min(64, deg - base);
    int sE = (lane < nin) ? csr[e0 + base + lane] : 0;
    float dvE = (lane < nin) ? dinv[sE] : 0.f;
    for (int j = 0; j < nin; j += 16){
      int   sA = __shfl(sE, j + g);
      float wA = __shfl(dvE, j + g) * dw;
      int   sB = __shfl(sE, j + 8 + g);
      float wB = __shfl(dvE, j + 8 + g) * dw;
      uint4 hA = H2[(size_t)sA*8 + li];
      uint4 hB = H2[(size_t)sB*8 + li];
      acc[0]=fmaf(wA,bflo(hA.x),acc[0]); acc[1]=fmaf(wA,bfhi(hA.x),acc[1]);
      acc[2]=fmaf(wA,bflo(hA.y),acc[2]); acc[3]=fmaf(wA,bfhi(hA.y),acc[3]);
      acc[4]=fmaf(wA,bflo(hA.z),acc[4]); acc[5]=fmaf(wA,bfhi(hA.z),acc[5]);
      acc[6]=fmaf(wA,bflo(hA.w),acc[6]); acc[7]=fmaf(wA,bfhi(hA.w),acc[7]);
      acc[0]=fmaf(wB,bflo(hB.x),acc[0]); acc[1]=fmaf(wB,bfhi(hB.x),acc[1]);
      acc[2]=fmaf(wB,bflo(hB.y),acc[2]); acc[3]=fmaf(wB,bfhi(hB.y),acc[3]);
      acc[4]=fmaf(wB,bflo(hB.z),acc[4]); acc[5]=fmaf(wB,bfhi(hB.z),acc[5]);
      acc[6]=fmaf(wB,bflo(hB.w),acc[6]); acc[7]=fmaf(wB,bfhi(hB.w),acc[7]);
    }
  }
  #pragma unroll
  for (int e = 0; e < 8; ++e){
    acc[e] += __shfl_xor(acc[e], 8);
    acc[e] += __shfl_xor(acc[e], 16);
    acc[e] += __shfl_xor(acc[e], 32);
  }
  float4 bA = *(const float4*)&b2[li*8];
  float4 bB = *(const float4*)&b2[li*8 + 4];
  acc[0]+=bA.x; acc[1]+=bA.y; acc[2]+=bA.z; acc[3]+=bA.w;
  acc[4]+=bB.x; acc[5]+=bB.y; acc[6]+=bB.z; acc[7]+=bB.w;
  if (g == 0){
    float4 o0 = make_float4(acc[0], acc[1], acc[2], acc[3]);
    float4 o1 = make_float4(acc[4], acc[5], acc[6], acc[7]);
    *(float4*)&out[(size_t)w*64 + li*8]     = o0;
    *(float4*)&out[(size_t)w*64 + li*8 + 4] = o1;
  }
}

extern "C" void kernel_launch(void* const* d_in, const int* in_sizes, int n_in,
                              void* d_out, int out_size, void* d_ws, size_t ws_size,
                              hipStream_t stream){
  const float* x  = (const float*)d_in[0];
  const int*   ei = (const int*)d_in[1];   // [2,E] int32
  const float* W1 = (const float*)d_in[2];
  const float* b1 = (const float*)d_in[3];
  const float* W2 = (const float*)d_in[4];
  const float* b2 = (const float*)d_in[5];
  float* out = (float*)d_out;

  int N = in_sizes[0] / 256;
  int E = in_sizes[1] / 2;
  int NB = (N + BSIZE - 1) >> BSHIFT;

  char* p = (char*)d_ws;
  uint32_t* H1   = (uint32_t*)p;  p += (size_t)N*64*4;    // [N,128] bf16
  uint32_t* A1   = (uint32_t*)p;  p += (size_t)N*64*4;    // [N,128] bf16
  uint32_t* H2   = (uint32_t*)p;  p += (size_t)N*32*4;    // [N,64]  bf16
  uint32_t* edgesP=(uint32_t*)p;  p += (size_t)E*4;       // bucket-grouped edges
  int* csr       = (int*)p;       p += (size_t)E*4;       // src-only CSR
  int* gHist     = (int*)p;       p += (size_t)NB*GPART*4;
  int* bucketTotal=(int*)p;       p += (size_t)((NB+63)&~63)*4;
  int* bucketBase= (int*)p;       p += (size_t)((NB+63)&~63)*4;
  uint4* W1f     = (uint4*)p;     p += 8*8*64*16;         // 64 KB
  uint4* W2f     = (uint4*)p;     p += 4*4*64*16;         // 16 KB
  int* start     = (int*)p;       p += (size_t)N*4;
  int* cnt       = (int*)p;       p += (size_t)N*4;
  float* dinv    = (float*)p;     p += (size_t)N*4;

  const int* srcIdx = ei;
  const int* dstIdx = ei + E;

  unsigned short* H1u = (unsigned short*)H1;

  int G1 = (N + 31) / 32;                   // total gemm1 tiles
  int sA = (int)((long)G1 * 20 / 100);
  int sB = (int)((long)G1 * 40 / 100);
  int sC = G1 - sA - sB;

  int nW2 = (N + 15) / 16;                  // gemm2: 1 wave per 16 rows
  int nG2Blocks = (nW2 + 3) / 4;
  int nNodeBlocks = (N + 3) / 4;            // aggs: 1 wave per node

  k_packW<<<(8*8*64 + 255)/256, 256, 0, stream>>>(W1, W1f, 256, 128);
  k_packW<<<(4*4*64 + 255)/256, 256, 0, stream>>>(W2, W2f, 128, 64);
  k_fat_hist<<<GPART + sA, 256, 0, stream>>>(dstIdx, E, NB, gHist,
      x, W1f, H1u, N, 0, GPART);
  k_scanA<<<NB, 64, 0, stream>>>(gHist, bucketTotal);
  k_scanB<<<1, 64, 0, stream>>>(bucketTotal, NB, bucketBase);
  k_fat_scatter<<<GPART + sB, 256, 0, stream>>>(srcIdx, dstIdx, E, NB, gHist, bucketBase,
      edgesP, x, W1f, H1u, N, sA, GPART);
  k_fat_p12<<<NB + sC, 256, 0, stream>>>(edgesP, bucketBase, bucketTotal, N, start, cnt, dinv,
      csr, x, W1f, H1u, sA + sB, NB);
  k_agg1<<<nNodeBlocks, 256, 0, stream>>>((const uint4*)H1, csr, start, cnt, dinv, b1, (uint4*)A1, N);
  k_gemm2_mfma<<<nG2Blocks, 256, 0, stream>>>((const uint4*)A1, W2f, (unsigned short*)H2, N);
  k_agg2<<<nNodeBlocks, 256, 0, stream>>>((const uint4*)H2, csr, start, cnt, dinv, b2, out, N);
}